// Round 12
// baseline (439.545 us; speedup 1.0000x reference)
//
#include <hip/hip_runtime.h>
#include <math.h>

#define NG 64
#define NM 256
#define ND 256
#define NK 16
#define NR (NG * NM)  // 16384 rows total
#define NB 32         // nodes per edge-MLP block

#define MASSF 0.9f

typedef _Float16 f16;
typedef __attribute__((ext_vector_type(8))) _Float16 f16x8;
typedef __attribute__((ext_vector_type(4))) _Float16 f16x4;
typedef __attribute__((ext_vector_type(4))) float f32x4;
typedef __attribute__((ext_vector_type(4))) unsigned u32x4;

// packed relu(a+b) on 2xf16
static __device__ __forceinline__ unsigned pkrelu(unsigned a, unsigned b) {
  unsigned r;
  asm("v_pk_add_f16 %0, %1, %2" : "=v"(r) : "v"(a), "v"(b));
  asm("v_pk_max_f16 %0, %1, %2" : "=v"(r) : "v"(r), "v"(0u));
  return r;
}

// ---------------- prep: W2^T (f16), W1cat = [W1hi - W1lo ; W1lo]^T (f16) ------
__global__ __launch_bounds__(256) void prep_k(const float* __restrict__ W1,
                                              const float* __restrict__ b1,
                                              const float* __restrict__ W2,
                                              f16* __restrict__ w2t, f16* __restrict__ w1cat,
                                              float* __restrict__ biascat) {
  const int b = blockIdx.x, k = threadIdx.x;
  if (b < 256) {
    w2t[b * 256 + k] = (f16)W2[(size_t)k * 256 + b];
  } else {
    const int n = b - 256;  // 0..511
    float v;
    if (n < 256)
      v = W1[(size_t)k * 256 + n] - W1[(size_t)(k + 256) * 256 + n];
    else
      v = W1[(size_t)(k + 256) * 256 + (n - 256)];
    w1cat[(size_t)n * 256 + k] = (f16)v;
    if (k == 0) biascat[n] = (n < 256) ? b1[n] : 0.f;
  }
}

// ------- encoder GEMM fp32 v3: 64x256 tile, 8x8 micro (strided cols) ---------
// C = relu(A@B + bias); also f16 copy. Thread (tx=tid&31, ty=tid>>5) owns
// rows m0+ty*8..+8, cols {tx+32j}. K sequential (bit-identical accumulation).
__global__ __launch_bounds__(256) void gemm_nn3_k(const float* __restrict__ A,
                                                  const float* __restrict__ B,
                                                  const float* __restrict__ bias,
                                                  float* __restrict__ C,
                                                  f16* __restrict__ Cf) {
  __shared__ float As[2][16][68];
  __shared__ float Bs[2][16][264];
  const int tid = threadIdx.x;
  const int tx = tid & 31, ty = tid >> 5;
  const int m0 = blockIdx.x * 64;
  const int arow = tid >> 2, akc = (tid & 3) * 4;
  const int bkr = tid >> 4, bcc = (tid & 15) * 16;
  float4 av, bv[4];
  float acc[8][8] = {};
  auto gload = [&](int k0) {
    av = *(const float4*)&A[(size_t)(m0 + arow) * 256 + k0 + akc];
#pragma unroll
    for (int q = 0; q < 4; ++q)
      bv[q] = *(const float4*)&B[(size_t)(k0 + bkr) * 256 + bcc + q * 4];
  };
  auto swrite = [&](int buf) {
    As[buf][akc + 0][arow] = av.x;
    As[buf][akc + 1][arow] = av.y;
    As[buf][akc + 2][arow] = av.z;
    As[buf][akc + 3][arow] = av.w;
#pragma unroll
    for (int q = 0; q < 4; ++q) *(float4*)&Bs[buf][bkr][bcc + q * 4] = bv[q];
  };
  gload(0);
  swrite(0);
  __syncthreads();
  for (int s = 0; s < 16; ++s) {
    if (s < 15) gload((s + 1) * 16);
    const int buf = s & 1;
#pragma unroll
    for (int kk = 0; kk < 16; ++kk) {
      float aa[8], bb[8];
      *(float4*)&aa[0] = *(const float4*)&As[buf][kk][ty * 8];
      *(float4*)&aa[4] = *(const float4*)&As[buf][kk][ty * 8 + 4];
#pragma unroll
      for (int j = 0; j < 8; ++j) bb[j] = Bs[buf][kk][tx + 32 * j];
#pragma unroll
      for (int i = 0; i < 8; ++i)
#pragma unroll
        for (int j = 0; j < 8; ++j) acc[i][j] = fmaf(aa[i], bb[j], acc[i][j]);
    }
    if (s < 15) swrite((s + 1) & 1);
    __syncthreads();
  }
  float bi[8];
#pragma unroll
  for (int j = 0; j < 8; ++j) bi[j] = bias[tx + 32 * j];
#pragma unroll
  for (int i = 0; i < 8; ++i) {
    const size_t row = (size_t)(m0 + ty * 8 + i);
#pragma unroll
    for (int j = 0; j < 8; ++j) {
      const float o = fmaxf(acc[i][j] + bi[j], 0.f);
      C[row * 256 + tx + 32 * j] = o;
      Cf[row * 256 + tx + 32 * j] = (f16)o;
    }
  }
}

// ------- gram NT fp32 v3: S_g = h_g @ h_g^T, 64x256 tile, fused diag ---------
__global__ __launch_bounds__(256) void gemm_nt3_k(const float* __restrict__ h,
                                                  float* __restrict__ C,
                                                  float* __restrict__ sq) {
  const int flat0 = blockIdx.x + 4 * blockIdx.y;      // 256 blocks
  const int flat = ((flat0 & 7) << 5) | (flat0 >> 3);  // XCD: 8 graphs each
  const int by = flat & 3, g = flat >> 2;
  __shared__ float As[2][16][68];
  __shared__ float Bs[2][16][264];
  const float* Ag = h + (size_t)g * NM * ND;
  float* Cg = C + (size_t)g * NM * NM;
  const int tid = threadIdx.x;
  const int tx = tid & 31, ty = tid >> 5;
  const int m0 = by * 64;
  const int arow = tid >> 2, akc = (tid & 3) * 4;
  float4 av, bv[4];
  float acc[8][8] = {};
  auto gload = [&](int k0) {
    av = *(const float4*)&Ag[(size_t)(m0 + arow) * 256 + k0 + akc];
#pragma unroll
    for (int q = 0; q < 4; ++q)
      bv[q] = *(const float4*)&Ag[(size_t)tid * 256 + k0 + q * 4];
  };
  auto swrite = [&](int buf) {
    As[buf][akc + 0][arow] = av.x;
    As[buf][akc + 1][arow] = av.y;
    As[buf][akc + 2][arow] = av.z;
    As[buf][akc + 3][arow] = av.w;
#pragma unroll
    for (int q = 0; q < 4; ++q) {
      Bs[buf][q * 4 + 0][tid] = bv[q].x;
      Bs[buf][q * 4 + 1][tid] = bv[q].y;
      Bs[buf][q * 4 + 2][tid] = bv[q].z;
      Bs[buf][q * 4 + 3][tid] = bv[q].w;
    }
  };
  gload(0);
  swrite(0);
  __syncthreads();
  for (int s = 0; s < 16; ++s) {
    if (s < 15) gload((s + 1) * 16);
    const int buf = s & 1;
#pragma unroll
    for (int kk = 0; kk < 16; ++kk) {
      float aa[8], bb[8];
      *(float4*)&aa[0] = *(const float4*)&As[buf][kk][ty * 8];
      *(float4*)&aa[4] = *(const float4*)&As[buf][kk][ty * 8 + 4];
#pragma unroll
      for (int j = 0; j < 8; ++j) bb[j] = Bs[buf][kk][tx + 32 * j];
#pragma unroll
      for (int i = 0; i < 8; ++i)
#pragma unroll
        for (int j = 0; j < 8; ++j) acc[i][j] = fmaf(aa[i], bb[j], acc[i][j]);
    }
    if (s < 15) swrite((s + 1) & 1);
    __syncthreads();
  }
#pragma unroll
  for (int i = 0; i < 8; ++i) {
    const int row = m0 + ty * 8 + i;
#pragma unroll
    for (int j = 0; j < 8; ++j) {
      const int col = tx + 32 * j;
      Cg[(size_t)row * 256 + col] = acc[i][j];
      if (row == col) sq[g * 256 + row] = acc[i][j];
    }
  }
}

// ---------------- MFMA GEMM: [16384,256]f16 @ w1cat^T -> baseb, n1b (f16) ----
__global__ __launch_bounds__(256, 2) void mlp1_mfma_k(const f16* __restrict__ A,
                                                      const f16* __restrict__ Bt,
                                                      const float* __restrict__ biascat,
                                                      f16* __restrict__ baseb,
                                                      f16* __restrict__ n1b) {
  __shared__ char As[64 * 512];
  const int tid = threadIdx.x;
  const int l = tid & 63, wv = tid >> 6;
  const int r = l & 15, gq = l >> 4;
  const int m0 = blockIdx.y * 64, n0 = blockIdx.x * 128;
  f16x8 bfr[2][8];
  float bv[2];
#pragma unroll
  for (int nt = 0; nt < 2; ++nt) {
    const int col = n0 + wv * 32 + nt * 16 + r;
    const f16* wb = Bt + (size_t)col * 256 + gq * 8;
#pragma unroll
    for (int ks = 0; ks < 8; ++ks) bfr[nt][ks] = *(const f16x8*)(wb + ks * 32);
    bv[nt] = biascat[col];
  }
  const int row = tid >> 2, ch = tid & 3;
  const char* ag = (const char*)(A + (size_t)(m0 + row) * 256) + ch * 128;
  char* lb = As + row * 512;
#pragma unroll
  for (int j = 0; j < 8; ++j)
    *(f16x8*)(lb + (((ch * 128 + j * 16)) ^ ((row & 7) << 4))) = *(const f16x8*)(ag + j * 16);
  __syncthreads();
  f32x4 acc[4][2];
#pragma unroll
  for (int mt = 0; mt < 4; ++mt)
#pragma unroll
    for (int nt = 0; nt < 2; ++nt) acc[mt][nt] = (f32x4){0.f, 0.f, 0.f, 0.f};
#pragma unroll
  for (int ks = 0; ks < 8; ++ks) {
    f16x8 a[4];
#pragma unroll
    for (int mt = 0; mt < 4; ++mt)
      a[mt] = *(const f16x8*)(As + (mt * 16 + r) * 512 + ((gq * 16 + ks * 64) ^ ((r & 7) << 4)));
#pragma unroll
    for (int mt = 0; mt < 4; ++mt)
#pragma unroll
      for (int nt = 0; nt < 2; ++nt)
        acc[mt][nt] = __builtin_amdgcn_mfma_f32_16x16x32_f16(a[mt], bfr[nt][ks], acc[mt][nt], 0, 0, 0);
  }
  f16* dst = (n0 < 256) ? baseb : n1b;
  const int cb = (n0 < 256) ? n0 : n0 - 256;
#pragma unroll
  for (int mt = 0; mt < 4; ++mt)
#pragma unroll
    for (int nt = 0; nt < 2; ++nt) {
      const int col = cb + wv * 32 + nt * 16 + r;
#pragma unroll
      for (int reg = 0; reg < 4; ++reg) {
        const int rw = m0 + mt * 16 + gq * 4 + reg;
        dst[(size_t)rw * 256 + col] = (f16)(acc[mt][nt][reg] + bv[nt]);
      }
    }
}

// ---------------- MFMA cost GEMM -> P0 = exp(corr/(nA nB lam)), XCD-swizzled --
__global__ __launch_bounds__(256, 2) void cost_mfma_k(const f16* __restrict__ featT,
                                                      const f16* __restrict__ featD,
                                                      const float* __restrict__ nA,
                                                      const float* __restrict__ nB,
                                                      const float* __restrict__ eps,
                                                      float* __restrict__ P) {
  __shared__ char As[64 * 512];
  const int flat = ((blockIdx.x & 7) << 6) | (blockIdx.x >> 3);
  const int bx = flat & 1, by = (flat >> 1) & 3, g = flat >> 3;
  const f16* A = featT + (size_t)g * NM * ND;
  const f16* Bt = featD + (size_t)g * NM * ND;
  const int tid = threadIdx.x;
  const int l = tid & 63, wv = tid >> 6;
  const int r = l & 15, gq = l >> 4;
  const int m0 = by * 64, n0 = bx * 128;
  f16x8 bfr[2][8];
  float rnb[2];
#pragma unroll
  for (int nt = 0; nt < 2; ++nt) {
    const int col = n0 + wv * 32 + nt * 16 + r;
    const f16* wb = Bt + (size_t)col * 256 + gq * 8;
#pragma unroll
    for (int ks = 0; ks < 8; ++ks) bfr[nt][ks] = *(const f16x8*)(wb + ks * 32);
    rnb[nt] = 1.0f / nB[g * NM + col];
  }
  const int row = tid >> 2, ch = tid & 3;
  const char* ag = (const char*)(A + (size_t)(m0 + row) * 256) + ch * 128;
  char* lb = As + row * 512;
#pragma unroll
  for (int j = 0; j < 8; ++j)
    *(f16x8*)(lb + (((ch * 128 + j * 16)) ^ ((row & 7) << 4))) = *(const f16x8*)(ag + j * 16);
  __syncthreads();
  f32x4 acc[4][2];
#pragma unroll
  for (int mt = 0; mt < 4; ++mt)
#pragma unroll
    for (int nt = 0; nt < 2; ++nt) acc[mt][nt] = (f32x4){0.f, 0.f, 0.f, 0.f};
#pragma unroll
  for (int ks = 0; ks < 8; ++ks) {
    f16x8 a[4];
#pragma unroll
    for (int mt = 0; mt < 4; ++mt)
      a[mt] = *(const f16x8*)(As + (mt * 16 + r) * 512 + ((gq * 16 + ks * 64) ^ ((r & 7) << 4)));
#pragma unroll
    for (int mt = 0; mt < 4; ++mt)
#pragma unroll
      for (int nt = 0; nt < 2; ++nt)
        acc[mt][nt] = __builtin_amdgcn_mfma_f32_16x16x32_f16(a[mt], bfr[nt][ks], acc[mt][nt], 0, 0, 0);
  }
  const float inv_lam = 1.0f / (expf(eps[0]) + 0.03f);
#pragma unroll
  for (int mt = 0; mt < 4; ++mt) {
    float ria[4];
#pragma unroll
    for (int reg = 0; reg < 4; ++reg)
      ria[reg] = inv_lam / nA[g * NM + m0 + mt * 16 + gq * 4 + reg];
#pragma unroll
    for (int nt = 0; nt < 2; ++nt) {
      const int col = n0 + wv * 32 + nt * 16 + r;
#pragma unroll
      for (int reg = 0; reg < 4; ++reg) {
        const int rw = m0 + mt * 16 + gq * 4 + reg;
        P[(size_t)g * NM * NM + (size_t)rw * 256 + col] =
            expf(acc[mt][nt][reg] * ria[reg] * rnb[nt]);
      }
    }
  }
}

// ---------------- top-16 nearest neighbors (wave per row) ----------------
__global__ __launch_bounds__(256) void topk_k(const float* __restrict__ S,
                                              const float* __restrict__ sq,
                                              int* __restrict__ idx) {
  const int w = threadIdx.x >> 6, lane = threadIdx.x & 63;
  const int row = blockIdx.x * 4 + w;
  const int g = row >> 8, m = row & 255;
  const float* Srow = S + (size_t)row * NM;
  const float* sqg = sq + g * NM;
  const float sm = sqg[m];
  const float4 sv = *(const float4*)&Srow[lane * 4];
  const float4 qv = *(const float4*)&sqg[lane * 4];
  float cand[4] = {sm + qv.x - 2.f * sv.x, sm + qv.y - 2.f * sv.y, sm + qv.z - 2.f * sv.z,
                   sm + qv.w - 2.f * sv.w};
#pragma unroll
  for (int t = 0; t < 4; ++t)
    if (lane * 4 + t == m) cand[t] = 1e30f;
  for (int rnd = 0; rnd < NK; ++rnd) {
    float bvv = cand[0];
    int bi = lane * 4;
#pragma unroll
    for (int t = 1; t < 4; ++t)
      if (cand[t] < bvv) {
        bvv = cand[t];
        bi = lane * 4 + t;
      }
#pragma unroll
    for (int off = 1; off < 64; off <<= 1) {
      const float ov = __shfl_xor(bvv, off);
      const int oi = __shfl_xor(bi, off);
      if (ov < bvv || (ov == bvv && oi < bi)) {
        bvv = ov;
        bi = oi;
      }
    }
    if (lane == 0) idx[(size_t)row * NK + rnd] = bi;
    if ((bi >> 2) == lane) cand[bi & 3] = 1e30f;
  }
}

// --------- edge MLP v10: v8 structure, merged over both graph-convs ----------
__global__ __launch_bounds__(512, 4) void edgemlp_mfma10_k(
    const f16* __restrict__ baseb2, const f16* __restrict__ n1b2, const int* __restrict__ idx2,
    const f16* __restrict__ w2t, const float* __restrict__ b2, f16* __restrict__ featf2,
    float* __restrict__ nrm2) {
  __shared__ unsigned E[2][2][512 * 4];  // [buf][node-in-pair][slot*4u] = 32 KB
  __shared__ int sidx[NB * NK];          // 512 ints
  __shared__ float normp[NB][8];
  const int tid = threadIdx.x;
  const int l = tid & 63, wv = tid >> 6;
  const size_t SZH = (size_t)NR * ND;
  const int bid = blockIdx.x;  // 0..1023
  const int half = bid >> 9;
  const int b9 = bid & 511;
  // XCD swizzle within half: each XCD gets 64 consecutive blocks = 8 graphs.
  const int blk = ((b9 & 7) << 6) | (b9 >> 3);
  const int node0 = blk * NB;
  const int g = node0 >> 8;
  const f16* baseb = baseb2 + (size_t)half * SZH;
  const f16* n1b = n1b2 + (size_t)half * SZH;
  const int* idx = idx2 + (size_t)half * NR * NK;
  f16* featf = featf2 + (size_t)half * SZH;
  float* nrm = nrm2 + (size_t)half * NR;
  const int r = l & 15, gq = l >> 4;
  sidx[tid] = idx[(size_t)node0 * NK + tid];
  f16x8 bfr[2][8];
  float b2v[2];
#pragma unroll
  for (int t = 0; t < 2; ++t) {
    const int nb = wv * 2 + t;
    const f16* wb = w2t + (size_t)(nb * 16 + r) * 256 + gq * 8;
#pragma unroll
    for (int ks = 0; ks < 8; ++ks) bfr[t][ks] = *(const f16x8*)(wb + ks * 32);
    b2v[t] = b2[nb * 16 + r];
  }
  __syncthreads();  // sidx visible
  const int r_s = tid & 15;
  const int col_s = ((tid >> 6) * 32) + (((tid >> 4) & 3) * 8);
  u32x4 bs0, ns0, bs1, ns1;
  auto sload = [&](int s) {
    const int na = s * 2;
    bs0 = *(const u32x4*)(baseb + (((size_t)(node0 + na)) << 8) + col_s);
    ns0 = *(const u32x4*)(n1b + ((((size_t)g << 8) + sidx[na * NK + r_s]) << 8) + col_s);
    bs1 = *(const u32x4*)(baseb + (((size_t)(node0 + na + 1)) << 8) + col_s);
    ns1 = *(const u32x4*)(n1b + ((((size_t)g << 8) + sidx[(na + 1) * NK + r_s]) << 8) + col_s);
  };
  auto swrite = [&](int s) {
    const int buf = s & 1;
    u32x4 w0, w1;
#pragma unroll
    for (int q = 0; q < 4; ++q) {
      w0[q] = pkrelu(bs0[q], ns0[q]);
      w1[q] = pkrelu(bs1[q], ns1[q]);
    }
    *(u32x4*)&E[buf][0][tid * 4] = w0;
    *(u32x4*)&E[buf][1][tid * 4] = w1;
  };
  sload(0);
  swrite(0);
  __syncthreads();
  for (int s = 0; s < NB / 2; ++s) {
    if (s + 1 < NB / 2) sload(s + 1);
    const int buf = s & 1;
#pragma unroll
    for (int q = 0; q < 2; ++q) {
      const char* eb = (const char*)&E[buf][q][0];
      f32x4 acc0 = (f32x4){0.f, 0.f, 0.f, 0.f};
      f32x4 acc1 = (f32x4){0.f, 0.f, 0.f, 0.f};
#pragma unroll
      for (int ks = 0; ks < 8; ++ks) {
        const f16x8 a = *(const f16x8*)(eb + ks * 1024 + l * 16);
        acc0 = __builtin_amdgcn_mfma_f32_16x16x32_f16(a, bfr[0][ks], acc0, 0, 0, 0);
        acc1 = __builtin_amdgcn_mfma_f32_16x16x32_f16(a, bfr[1][ks], acc1, 0, 0, 0);
      }
      const int nd = node0 + s * 2 + q;
      float m0v = fmaxf(fmaxf(acc0[0], acc0[1]), fmaxf(acc0[2], acc0[3]));
      m0v = fmaxf(m0v, __shfl_xor(m0v, 16));
      m0v = fmaxf(m0v, __shfl_xor(m0v, 32));
      float m1v = fmaxf(fmaxf(acc1[0], acc1[1]), fmaxf(acc1[2], acc1[3]));
      m1v = fmaxf(m1v, __shfl_xor(m1v, 16));
      m1v = fmaxf(m1v, __shfl_xor(m1v, 32));
      const f16 h0 = (f16)(m0v + b2v[0]);
      const f16 h1 = (f16)(m1v + b2v[1]);
      if (gq == 0) {
        featf[((size_t)nd << 8) + (wv * 2 + 0) * 16 + r] = h0;
        featf[((size_t)nd << 8) + (wv * 2 + 1) * 16 + r] = h1;
      }
      const float o0 = (float)h0, o1 = (float)h1;
      float ss = o0 * o0 + o1 * o1;
      ss += __shfl_xor(ss, 1);
      ss += __shfl_xor(ss, 2);
      ss += __shfl_xor(ss, 4);
      ss += __shfl_xor(ss, 8);
      if (l == 0) normp[s * 2 + q][wv] = ss;
    }
    if (s + 1 < NB / 2) swrite(s + 1);
    __syncthreads();
  }
  if (tid < NB) {
    float s = 0.f;
#pragma unroll
    for (int w = 0; w < 8; ++w) s += normp[tid][w];
    nrm[node0 + tid] = sqrtf(s);
  }
}

// ---------------- fused Sinkhorn, plain domain: block per graph, P in regs ----
__global__ __launch_bounds__(1024) void sinkhorn_k(float* __restrict__ P) {
  __shared__ float red[16][256];
  __shared__ float scal[256];
  const int t = threadIdx.x;
  const int tc = t & 15;
  const int trw = t >> 4;
  const int wv = t >> 6, l = t & 63;
  float* Pg = P + (size_t)blockIdx.x * NM * NM;
  float p[4][16];
#pragma unroll
  for (int i = 0; i < 4; ++i)
#pragma unroll
    for (int q = 0; q < 4; ++q)
      *(f32x4*)&p[i][q * 4] = *(const f32x4*)&Pg[(size_t)(trw * 4 + i) * NM + tc * 16 + q * 4];

  auto rowpass = [&]() {
#pragma unroll
    for (int i = 0; i < 4; ++i) {
      float s = p[i][0];
#pragma unroll
      for (int j = 1; j < 16; ++j) s += p[i][j];
      s += __shfl_xor(s, 1);
      s += __shfl_xor(s, 2);
      s += __shfl_xor(s, 4);
      s += __shfl_xor(s, 8);
      const float sc = MASSF / s;
#pragma unroll
      for (int j = 0; j < 16; ++j) p[i][j] *= sc;
    }
  };
  auto colpass = [&]() {
    float tmp[16];
#pragma unroll
    for (int j = 0; j < 16; ++j) tmp[j] = ((p[0][j] + p[1][j]) + (p[2][j] + p[3][j]));
#pragma unroll
    for (int j = 0; j < 16; ++j) {
      tmp[j] += __shfl_xor(tmp[j], 16);
      tmp[j] += __shfl_xor(tmp[j], 32);
    }
    if (l < 16) {
#pragma unroll
      for (int q = 0; q < 4; ++q)
        *(f32x4*)&red[wv][l * 16 + q * 4] = *(const f32x4*)&tmp[q * 4];
    }
    __syncthreads();
    if (t < 256) {
      float s = red[0][t];
#pragma unroll
      for (int w = 1; w < 16; ++w) s += red[w][t];
      scal[t] = MASSF / s;
    }
    __syncthreads();
#pragma unroll
    for (int j = 0; j < 16; ++j) {
      const float sc = scal[tc * 16 + j];
#pragma unroll
      for (int i = 0; i < 4; ++i) p[i][j] *= sc;
    }
    __syncthreads();
  };
  for (int it = 0; it < 7; ++it) {
    rowpass();
    colpass();
  }
  rowpass();
#pragma unroll
  for (int i = 0; i < 4; ++i)
#pragma unroll
    for (int q = 0; q < 4; ++q)
      *(f32x4*)&Pg[(size_t)(trw * 4 + i) * NM + tc * 16 + q * 4] = *(const f32x4*)&p[i][q * 4];
}

extern "C" void kernel_launch(void* const* d_in, const int* in_sizes, int n_in, void* d_out,
                              int out_size, void* d_ws, size_t ws_size, hipStream_t stream) {
  const float* tra_x = (const float*)d_in[0];
  const float* det_x = (const float*)d_in[1];
  const float* W_enc = (const float*)d_in[2];
  const float* b_enc = (const float*)d_in[3];
  const float* W1 = (const float*)d_in[4];
  const float* b1 = (const float*)d_in[5];
  const float* W2 = (const float*)d_in[6];
  const float* b2 = (const float*)d_in[7];
  const float* eps = (const float*)d_in[8];
  float* out = (float*)d_out;

  const size_t SZ = (size_t)NR * ND;
  float* h = (float*)d_ws;         // SZ fp32
  f16* hf = (f16*)(h + SZ);        // SZ f16 (reused per s2)
  f16* baseb = hf + SZ;            // 2*SZ f16
  f16* n1b = baseb + 2 * SZ;       // 2*SZ f16
  f16* featT = n1b + 2 * SZ;       // SZ
  f16* featD = featT + SZ;         // SZ (contiguous with featT)
  float* sq = (float*)(featD + SZ);
  float* nT = sq + NR;             // NR ; nD contiguous
  float* nD = nT + NR;
  int* idx = (int*)(nD + NR);      // 2*NR*NK
  f16* w2t = (f16*)(idx + 2 * (size_t)NR * NK);
  f16* w1cat = w2t + 256 * 256;
  float* biascat = (float*)(w1cat + 512 * 256);
  float* S = out;  // gram scratch lives in d_out until cost overwrites it

  const float* xs[2] = {tra_x, det_x};

  prep_k<<<768, 256, 0, stream>>>(W1, b1, W2, w2t, w1cat, biascat);
  for (int s2 = 0; s2 < 2; ++s2) {
    gemm_nn3_k<<<256, 256, 0, stream>>>(xs[s2], W_enc, b_enc, h, hf);
    mlp1_mfma_k<<<dim3(4, 256), 256, 0, stream>>>(hf, w1cat, biascat, baseb + s2 * SZ,
                                                  n1b + s2 * SZ);
    gemm_nt3_k<<<dim3(4, 64), 256, 0, stream>>>(h, S, sq);
    topk_k<<<4096, 256, 0, stream>>>(S, sq, idx + (size_t)s2 * NR * NK);
  }
  edgemlp_mfma10_k<<<1024, 512, 0, stream>>>(baseb, n1b, idx, w2t, b2, featT, nT);
  cost_mfma_k<<<512, 256, 0, stream>>>(featT, featD, nT, nD, eps, out);
  sinkhorn_k<<<NG, 1024, 0, stream>>>(out);
}

// Round 13
// 371.738 us; speedup vs baseline: 1.1824x; 1.1824x over previous
//
#include <hip/hip_runtime.h>
#include <math.h>

#define NG 64
#define NM 256
#define ND 256
#define NK 16
#define NR (NG * NM)  // 16384 rows total
#define NB 32         // nodes per edge-MLP block

#define MASSF 0.9f

typedef _Float16 f16;
typedef __attribute__((ext_vector_type(8))) _Float16 f16x8;
typedef __attribute__((ext_vector_type(4))) _Float16 f16x4;
typedef __attribute__((ext_vector_type(4))) float f32x4;
typedef __attribute__((ext_vector_type(4))) unsigned u32x4;

// packed relu(a+b) on 2xf16
static __device__ __forceinline__ unsigned pkrelu(unsigned a, unsigned b) {
  unsigned r;
  asm("v_pk_add_f16 %0, %1, %2" : "=v"(r) : "v"(a), "v"(b));
  asm("v_pk_max_f16 %0, %1, %2" : "=v"(r) : "v"(r), "v"(0u));
  return r;
}

// ---------------- prep: W2^T (f16), W1cat = [W1hi - W1lo ; W1lo]^T (f16) ------
__global__ __launch_bounds__(256) void prep_k(const float* __restrict__ W1,
                                              const float* __restrict__ b1,
                                              const float* __restrict__ W2,
                                              f16* __restrict__ w2t, f16* __restrict__ w1cat,
                                              float* __restrict__ biascat) {
  const int b = blockIdx.x, k = threadIdx.x;
  if (b < 256) {
    w2t[b * 256 + k] = (f16)W2[(size_t)k * 256 + b];
  } else {
    const int n = b - 256;  // 0..511
    float v;
    if (n < 256)
      v = W1[(size_t)k * 256 + n] - W1[(size_t)(k + 256) * 256 + n];
    else
      v = W1[(size_t)(k + 256) * 256 + (n - 256)];
    w1cat[(size_t)n * 256 + k] = (f16)v;
    if (k == 0) biascat[n] = (n < 256) ? b1[n] : 0.f;
  }
}

// ---------------- encoder GEMM fp32: C = relu(A@B + bias), + f16 copy --------
// 64x128 tile, 4x8 split micro-tile, dbuf LDS, 1 barrier/K-step. (round-10 proven)
__global__ __launch_bounds__(256) void gemm_nn2_k(const float* __restrict__ A,
                                                  const float* __restrict__ B,
                                                  const float* __restrict__ bias,
                                                  float* __restrict__ C,
                                                  f16* __restrict__ Cf) {
  __shared__ float As[2][16][68];
  __shared__ float Bs[2][16][128];
  const int tid = threadIdx.x;
  const int tx = tid & 15, ty = tid >> 4;
  const int m0 = blockIdx.y * 64, n0 = blockIdx.x * 128;
  const int arow = tid >> 2, akc = (tid & 3) * 4;
  const int bkr = tid >> 4, bcc = (tid & 15) * 4;
  float4 av, bv0, bv1;
  float acc[4][8] = {};
  auto gload = [&](int k0) {
    av = *(const float4*)&A[(size_t)(m0 + arow) * 256 + k0 + akc];
    bv0 = *(const float4*)&B[(size_t)(k0 + bkr) * 256 + n0 + bcc];
    bv1 = *(const float4*)&B[(size_t)(k0 + bkr) * 256 + n0 + 64 + bcc];
  };
  auto swrite = [&](int buf) {
    As[buf][akc + 0][arow] = av.x;
    As[buf][akc + 1][arow] = av.y;
    As[buf][akc + 2][arow] = av.z;
    As[buf][akc + 3][arow] = av.w;
    *(float4*)&Bs[buf][bkr][bcc] = bv0;
    *(float4*)&Bs[buf][bkr][64 + bcc] = bv1;
  };
  gload(0);
  swrite(0);
  __syncthreads();
  for (int s = 0; s < 16; ++s) {
    if (s < 15) gload((s + 1) * 16);
    const int buf = s & 1;
#pragma unroll
    for (int kk = 0; kk < 16; ++kk) {
      const float4 a0 = *(const float4*)&As[buf][kk][ty * 4];
      const float4 b0 = *(const float4*)&Bs[buf][kk][tx * 4];
      const float4 b1 = *(const float4*)&Bs[buf][kk][64 + tx * 4];
      const float aa[4] = {a0.x, a0.y, a0.z, a0.w};
      const float bb[8] = {b0.x, b0.y, b0.z, b0.w, b1.x, b1.y, b1.z, b1.w};
#pragma unroll
      for (int i = 0; i < 4; ++i)
#pragma unroll
        for (int j = 0; j < 8; ++j) acc[i][j] = fmaf(aa[i], bb[j], acc[i][j]);
    }
    if (s < 15) swrite((s + 1) & 1);
    __syncthreads();
  }
  const float4 bia0 = *(const float4*)&bias[n0 + tx * 4];
  const float4 bia1 = *(const float4*)&bias[n0 + 64 + tx * 4];
#pragma unroll
  for (int i = 0; i < 4; ++i) {
    const size_t row = (size_t)(m0 + ty * 4 + i);
    float4 o0 = {fmaxf(acc[i][0] + bia0.x, 0.f), fmaxf(acc[i][1] + bia0.y, 0.f),
                 fmaxf(acc[i][2] + bia0.z, 0.f), fmaxf(acc[i][3] + bia0.w, 0.f)};
    float4 o1 = {fmaxf(acc[i][4] + bia1.x, 0.f), fmaxf(acc[i][5] + bia1.y, 0.f),
                 fmaxf(acc[i][6] + bia1.z, 0.f), fmaxf(acc[i][7] + bia1.w, 0.f)};
    *(float4*)&C[row * 256 + n0 + tx * 4] = o0;
    *(float4*)&C[row * 256 + n0 + 64 + tx * 4] = o1;
    f16x4 h0 = {(f16)o0.x, (f16)o0.y, (f16)o0.z, (f16)o0.w};
    f16x4 h1 = {(f16)o1.x, (f16)o1.y, (f16)o1.z, (f16)o1.w};
    *(f16x4*)&Cf[row * 256 + n0 + tx * 4] = h0;
    *(f16x4*)&Cf[row * 256 + n0 + 64 + tx * 4] = h1;
  }
}

// ---------------- symmetric gram NT fp32 per graph + fused diagonal ----------
__global__ __launch_bounds__(256) void gemm_nt2_k(const float* __restrict__ h,
                                                  float* __restrict__ C,
                                                  float* __restrict__ sq) {
  const int flat0 = blockIdx.x + 2 * (blockIdx.y + 4 * blockIdx.z);
  const int flat = ((flat0 & 7) << 6) | (flat0 >> 3);  // 512 blocks: %8 *64 + /8
  const int bx = flat & 1, by = (flat >> 1) & 3, g = flat >> 3;
  if (bx == 0 && by >= 2) return;  // covered by mirror of (bx=1, by<2)
  __shared__ float As[2][16][68];
  __shared__ float Bs[2][16][128];
  const float* Ag = h + (size_t)g * NM * ND;
  float* Cg = C + (size_t)g * NM * NM;
  const int tid = threadIdx.x;
  const int tx = tid & 15, ty = tid >> 4;
  const int m0 = by * 64, n0 = bx * 128;
  const int arow = tid >> 2, akc = (tid & 3) * 4;
  const int brow = tid >> 1, bkc = (tid & 1) * 8;
  float4 av, bva, bvb;
  float acc[4][8] = {};
  auto gload = [&](int k0) {
    av = *(const float4*)&Ag[(size_t)(m0 + arow) * 256 + k0 + akc];
    bva = *(const float4*)&Ag[(size_t)(n0 + brow) * 256 + k0 + bkc];
    bvb = *(const float4*)&Ag[(size_t)(n0 + brow) * 256 + k0 + bkc + 4];
  };
  auto swrite = [&](int buf) {
    As[buf][akc + 0][arow] = av.x;
    As[buf][akc + 1][arow] = av.y;
    As[buf][akc + 2][arow] = av.z;
    As[buf][akc + 3][arow] = av.w;
    Bs[buf][bkc + 0][brow] = bva.x;
    Bs[buf][bkc + 1][brow] = bva.y;
    Bs[buf][bkc + 2][brow] = bva.z;
    Bs[buf][bkc + 3][brow] = bva.w;
    Bs[buf][bkc + 4][brow] = bvb.x;
    Bs[buf][bkc + 5][brow] = bvb.y;
    Bs[buf][bkc + 6][brow] = bvb.z;
    Bs[buf][bkc + 7][brow] = bvb.w;
  };
  gload(0);
  swrite(0);
  __syncthreads();
  for (int s = 0; s < 16; ++s) {
    if (s < 15) gload((s + 1) * 16);
    const int buf = s & 1;
#pragma unroll
    for (int kk = 0; kk < 16; ++kk) {
      const float4 a0 = *(const float4*)&As[buf][kk][ty * 4];
      const float4 b0 = *(const float4*)&Bs[buf][kk][tx * 4];
      const float4 b1 = *(const float4*)&Bs[buf][kk][64 + tx * 4];
      const float aa[4] = {a0.x, a0.y, a0.z, a0.w};
      const float bb[8] = {b0.x, b0.y, b0.z, b0.w, b1.x, b1.y, b1.z, b1.w};
#pragma unroll
      for (int i = 0; i < 4; ++i)
#pragma unroll
        for (int j = 0; j < 8; ++j) acc[i][j] = fmaf(aa[i], bb[j], acc[i][j]);
    }
    if (s < 15) swrite((s + 1) & 1);
    __syncthreads();
  }
  const int c0 = n0 + tx * 4, c1 = n0 + 64 + tx * 4;
#pragma unroll
  for (int i = 0; i < 4; ++i) {
    const int row = m0 + ty * 4 + i;
    float4 o0 = {acc[i][0], acc[i][1], acc[i][2], acc[i][3]};
    float4 o1 = {acc[i][4], acc[i][5], acc[i][6], acc[i][7]};
    *(float4*)&Cg[(size_t)row * 256 + c0] = o0;
    *(float4*)&Cg[(size_t)row * 256 + c1] = o1;
    if (row >= c0 && row < c0 + 4) sq[g * 256 + row] = acc[i][row - c0];
    if (row >= c1 && row < c1 + 4) sq[g * 256 + row] = acc[i][4 + row - c1];
  }
  if (bx == 1 && by < 2) {  // mirror into the skipped lower-left region
#pragma unroll
    for (int j = 0; j < 4; ++j) {
      const size_t col0 = (size_t)(n0 + tx * 4 + j);
      const size_t col1 = (size_t)(n0 + 64 + tx * 4 + j);
      float4 t0 = {acc[0][j], acc[1][j], acc[2][j], acc[3][j]};
      float4 t1 = {acc[0][4 + j], acc[1][4 + j], acc[2][4 + j], acc[3][4 + j]};
      *(float4*)&Cg[col0 * 256 + m0 + ty * 4] = t0;
      *(float4*)&Cg[col1 * 256 + m0 + ty * 4] = t1;
    }
  }
}

// ---------------- MFMA GEMM: [16384,256]f16 @ w1cat^T -> baseb, n1b (f16) ----
__global__ __launch_bounds__(256, 2) void mlp1_mfma_k(const f16* __restrict__ A,
                                                      const f16* __restrict__ Bt,
                                                      const float* __restrict__ biascat,
                                                      f16* __restrict__ baseb,
                                                      f16* __restrict__ n1b) {
  __shared__ char As[64 * 512];
  const int tid = threadIdx.x;
  const int l = tid & 63, wv = tid >> 6;
  const int r = l & 15, gq = l >> 4;
  const int m0 = blockIdx.y * 64, n0 = blockIdx.x * 128;
  f16x8 bfr[2][8];
  float bv[2];
#pragma unroll
  for (int nt = 0; nt < 2; ++nt) {
    const int col = n0 + wv * 32 + nt * 16 + r;
    const f16* wb = Bt + (size_t)col * 256 + gq * 8;
#pragma unroll
    for (int ks = 0; ks < 8; ++ks) bfr[nt][ks] = *(const f16x8*)(wb + ks * 32);
    bv[nt] = biascat[col];
  }
  const int row = tid >> 2, ch = tid & 3;
  const char* ag = (const char*)(A + (size_t)(m0 + row) * 256) + ch * 128;
  char* lb = As + row * 512;
#pragma unroll
  for (int j = 0; j < 8; ++j)
    *(f16x8*)(lb + (((ch * 128 + j * 16)) ^ ((row & 7) << 4))) = *(const f16x8*)(ag + j * 16);
  __syncthreads();
  f32x4 acc[4][2];
#pragma unroll
  for (int mt = 0; mt < 4; ++mt)
#pragma unroll
    for (int nt = 0; nt < 2; ++nt) acc[mt][nt] = (f32x4){0.f, 0.f, 0.f, 0.f};
#pragma unroll
  for (int ks = 0; ks < 8; ++ks) {
    f16x8 a[4];
#pragma unroll
    for (int mt = 0; mt < 4; ++mt)
      a[mt] = *(const f16x8*)(As + (mt * 16 + r) * 512 + ((gq * 16 + ks * 64) ^ ((r & 7) << 4)));
#pragma unroll
    for (int mt = 0; mt < 4; ++mt)
#pragma unroll
      for (int nt = 0; nt < 2; ++nt)
        acc[mt][nt] = __builtin_amdgcn_mfma_f32_16x16x32_f16(a[mt], bfr[nt][ks], acc[mt][nt], 0, 0, 0);
  }
  f16* dst = (n0 < 256) ? baseb : n1b;
  const int cb = (n0 < 256) ? n0 : n0 - 256;
#pragma unroll
  for (int mt = 0; mt < 4; ++mt)
#pragma unroll
    for (int nt = 0; nt < 2; ++nt) {
      const int col = cb + wv * 32 + nt * 16 + r;
#pragma unroll
      for (int reg = 0; reg < 4; ++reg) {
        const int rw = m0 + mt * 16 + gq * 4 + reg;
        dst[(size_t)rw * 256 + col] = (f16)(acc[mt][nt][reg] + bv[nt]);
      }
    }
}

// ---------------- MFMA cost GEMM -> P0 = exp(corr/(nA nB lam)), XCD-swizzled --
__global__ __launch_bounds__(256, 2) void cost_mfma_k(const f16* __restrict__ featT,
                                                      const f16* __restrict__ featD,
                                                      const float* __restrict__ nA,
                                                      const float* __restrict__ nB,
                                                      const float* __restrict__ eps,
                                                      float* __restrict__ P) {
  __shared__ char As[64 * 512];
  const int flat = ((blockIdx.x & 7) << 6) | (blockIdx.x >> 3);
  const int bx = flat & 1, by = (flat >> 1) & 3, g = flat >> 3;
  const f16* A = featT + (size_t)g * NM * ND;
  const f16* Bt = featD + (size_t)g * NM * ND;
  const int tid = threadIdx.x;
  const int l = tid & 63, wv = tid >> 6;
  const int r = l & 15, gq = l >> 4;
  const int m0 = by * 64, n0 = bx * 128;
  f16x8 bfr[2][8];
  float rnb[2];
#pragma unroll
  for (int nt = 0; nt < 2; ++nt) {
    const int col = n0 + wv * 32 + nt * 16 + r;
    const f16* wb = Bt + (size_t)col * 256 + gq * 8;
#pragma unroll
    for (int ks = 0; ks < 8; ++ks) bfr[nt][ks] = *(const f16x8*)(wb + ks * 32);
    rnb[nt] = 1.0f / nB[g * NM + col];
  }
  const int row = tid >> 2, ch = tid & 3;
  const char* ag = (const char*)(A + (size_t)(m0 + row) * 256) + ch * 128;
  char* lb = As + row * 512;
#pragma unroll
  for (int j = 0; j < 8; ++j)
    *(f16x8*)(lb + (((ch * 128 + j * 16)) ^ ((row & 7) << 4))) = *(const f16x8*)(ag + j * 16);
  __syncthreads();
  f32x4 acc[4][2];
#pragma unroll
  for (int mt = 0; mt < 4; ++mt)
#pragma unroll
    for (int nt = 0; nt < 2; ++nt) acc[mt][nt] = (f32x4){0.f, 0.f, 0.f, 0.f};
#pragma unroll
  for (int ks = 0; ks < 8; ++ks) {
    f16x8 a[4];
#pragma unroll
    for (int mt = 0; mt < 4; ++mt)
      a[mt] = *(const f16x8*)(As + (mt * 16 + r) * 512 + ((gq * 16 + ks * 64) ^ ((r & 7) << 4)));
#pragma unroll
    for (int mt = 0; mt < 4; ++mt)
#pragma unroll
      for (int nt = 0; nt < 2; ++nt)
        acc[mt][nt] = __builtin_amdgcn_mfma_f32_16x16x32_f16(a[mt], bfr[nt][ks], acc[mt][nt], 0, 0, 0);
  }
  const float inv_lam = 1.0f / (expf(eps[0]) + 0.03f);
#pragma unroll
  for (int mt = 0; mt < 4; ++mt) {
    float ria[4];
#pragma unroll
    for (int reg = 0; reg < 4; ++reg)
      ria[reg] = inv_lam / nA[g * NM + m0 + mt * 16 + gq * 4 + reg];
#pragma unroll
    for (int nt = 0; nt < 2; ++nt) {
      const int col = n0 + wv * 32 + nt * 16 + r;
#pragma unroll
      for (int reg = 0; reg < 4; ++reg) {
        const int rw = m0 + mt * 16 + gq * 4 + reg;
        P[(size_t)g * NM * NM + (size_t)rw * 256 + col] =
            expf(acc[mt][nt][reg] * ria[reg] * rnb[nt]);
      }
    }
  }
}

// ---------------- top-16 nearest neighbors (wave per row) ----------------
__global__ __launch_bounds__(256) void topk_k(const float* __restrict__ S,
                                              const float* __restrict__ sq,
                                              int* __restrict__ idx) {
  const int w = threadIdx.x >> 6, lane = threadIdx.x & 63;
  const int row = blockIdx.x * 4 + w;
  const int g = row >> 8, m = row & 255;
  const float* Srow = S + (size_t)row * NM;
  const float* sqg = sq + g * NM;
  const float sm = sqg[m];
  const float4 sv = *(const float4*)&Srow[lane * 4];
  const float4 qv = *(const float4*)&sqg[lane * 4];
  float cand[4] = {sm + qv.x - 2.f * sv.x, sm + qv.y - 2.f * sv.y, sm + qv.z - 2.f * sv.z,
                   sm + qv.w - 2.f * sv.w};
#pragma unroll
  for (int t = 0; t < 4; ++t)
    if (lane * 4 + t == m) cand[t] = 1e30f;
  for (int rnd = 0; rnd < NK; ++rnd) {
    float bvv = cand[0];
    int bi = lane * 4;
#pragma unroll
    for (int t = 1; t < 4; ++t)
      if (cand[t] < bvv) {
        bvv = cand[t];
        bi = lane * 4 + t;
      }
#pragma unroll
    for (int off = 1; off < 64; off <<= 1) {
      const float ov = __shfl_xor(bvv, off);
      const int oi = __shfl_xor(bi, off);
      if (ov < bvv || (ov == bvv && oi < bi)) {
        bvv = ov;
        bi = oi;
      }
    }
    if (lane == 0) idx[(size_t)row * NK + rnd] = bi;
    if ((bi >> 2) == lane) cand[bi & 3] = 1e30f;
  }
}

// --------- edge MLP v10: v8 structure, merged over both graph-convs ----------
__global__ __launch_bounds__(512, 4) void edgemlp_mfma10_k(
    const f16* __restrict__ baseb2, const f16* __restrict__ n1b2, const int* __restrict__ idx2,
    const f16* __restrict__ w2t, const float* __restrict__ b2, f16* __restrict__ featf2,
    float* __restrict__ nrm2) {
  __shared__ unsigned E[2][2][512 * 4];  // [buf][node-in-pair][slot*4u] = 32 KB
  __shared__ int sidx[NB * NK];          // 512 ints
  __shared__ float normp[NB][8];
  const int tid = threadIdx.x;
  const int l = tid & 63, wv = tid >> 6;
  const size_t SZH = (size_t)NR * ND;
  const int bid = blockIdx.x;  // 0..1023
  const int half = bid >> 9;
  const int b9 = bid & 511;
  const int blk = ((b9 & 7) << 6) | (b9 >> 3);  // XCD: 8 graphs each
  const int node0 = blk * NB;
  const int g = node0 >> 8;
  const f16* baseb = baseb2 + (size_t)half * SZH;
  const f16* n1b = n1b2 + (size_t)half * SZH;
  const int* idx = idx2 + (size_t)half * NR * NK;
  f16* featf = featf2 + (size_t)half * SZH;
  float* nrm = nrm2 + (size_t)half * NR;
  const int r = l & 15, gq = l >> 4;
  sidx[tid] = idx[(size_t)node0 * NK + tid];
  f16x8 bfr[2][8];
  float b2v[2];
#pragma unroll
  for (int t = 0; t < 2; ++t) {
    const int nb = wv * 2 + t;
    const f16* wb = w2t + (size_t)(nb * 16 + r) * 256 + gq * 8;
#pragma unroll
    for (int ks = 0; ks < 8; ++ks) bfr[t][ks] = *(const f16x8*)(wb + ks * 32);
    b2v[t] = b2[nb * 16 + r];
  }
  __syncthreads();  // sidx visible
  const int r_s = tid & 15;
  const int col_s = ((tid >> 6) * 32) + (((tid >> 4) & 3) * 8);
  u32x4 bs0, ns0, bs1, ns1;
  auto sload = [&](int s) {
    const int na = s * 2;
    bs0 = *(const u32x4*)(baseb + (((size_t)(node0 + na)) << 8) + col_s);
    ns0 = *(const u32x4*)(n1b + ((((size_t)g << 8) + sidx[na * NK + r_s]) << 8) + col_s);
    bs1 = *(const u32x4*)(baseb + (((size_t)(node0 + na + 1)) << 8) + col_s);
    ns1 = *(const u32x4*)(n1b + ((((size_t)g << 8) + sidx[(na + 1) * NK + r_s]) << 8) + col_s);
  };
  auto swrite = [&](int s) {
    const int buf = s & 1;
    u32x4 w0, w1;
#pragma unroll
    for (int q = 0; q < 4; ++q) {
      w0[q] = pkrelu(bs0[q], ns0[q]);
      w1[q] = pkrelu(bs1[q], ns1[q]);
    }
    *(u32x4*)&E[buf][0][tid * 4] = w0;
    *(u32x4*)&E[buf][1][tid * 4] = w1;
  };
  sload(0);
  swrite(0);
  __syncthreads();
  for (int s = 0; s < NB / 2; ++s) {
    if (s + 1 < NB / 2) sload(s + 1);
    const int buf = s & 1;
#pragma unroll
    for (int q = 0; q < 2; ++q) {
      const char* eb = (const char*)&E[buf][q][0];
      f32x4 acc0 = (f32x4){0.f, 0.f, 0.f, 0.f};
      f32x4 acc1 = (f32x4){0.f, 0.f, 0.f, 0.f};
#pragma unroll
      for (int ks = 0; ks < 8; ++ks) {
        const f16x8 a = *(const f16x8*)(eb + ks * 1024 + l * 16);
        acc0 = __builtin_amdgcn_mfma_f32_16x16x32_f16(a, bfr[0][ks], acc0, 0, 0, 0);
        acc1 = __builtin_amdgcn_mfma_f32_16x16x32_f16(a, bfr[1][ks], acc1, 0, 0, 0);
      }
      const int nd = node0 + s * 2 + q;
      float m0v = fmaxf(fmaxf(acc0[0], acc0[1]), fmaxf(acc0[2], acc0[3]));
      m0v = fmaxf(m0v, __shfl_xor(m0v, 16));
      m0v = fmaxf(m0v, __shfl_xor(m0v, 32));
      float m1v = fmaxf(fmaxf(acc1[0], acc1[1]), fmaxf(acc1[2], acc1[3]));
      m1v = fmaxf(m1v, __shfl_xor(m1v, 16));
      m1v = fmaxf(m1v, __shfl_xor(m1v, 32));
      const f16 h0 = (f16)(m0v + b2v[0]);
      const f16 h1 = (f16)(m1v + b2v[1]);
      if (gq == 0) {
        featf[((size_t)nd << 8) + (wv * 2 + 0) * 16 + r] = h0;
        featf[((size_t)nd << 8) + (wv * 2 + 1) * 16 + r] = h1;
      }
      const float o0 = (float)h0, o1 = (float)h1;
      float ss = o0 * o0 + o1 * o1;
      ss += __shfl_xor(ss, 1);
      ss += __shfl_xor(ss, 2);
      ss += __shfl_xor(ss, 4);
      ss += __shfl_xor(ss, 8);
      if (l == 0) normp[s * 2 + q][wv] = ss;
    }
    if (s + 1 < NB / 2) swrite(s + 1);
    __syncthreads();
  }
  if (tid < NB) {
    float s = 0.f;
#pragma unroll
    for (int w = 0; w < 8; ++w) s += normp[tid][w];
    nrm[node0 + tid] = sqrtf(s);
  }
}

// ---------------- fused Sinkhorn, plain domain: block per graph, P in regs ----
__global__ __launch_bounds__(1024) void sinkhorn_k(float* __restrict__ P) {
  __shared__ float red[16][256];
  __shared__ float scal[256];
  const int t = threadIdx.x;
  const int tc = t & 15;
  const int trw = t >> 4;
  const int wv = t >> 6, l = t & 63;
  float* Pg = P + (size_t)blockIdx.x * NM * NM;
  float p[4][16];
#pragma unroll
  for (int i = 0; i < 4; ++i)
#pragma unroll
    for (int q = 0; q < 4; ++q)
      *(f32x4*)&p[i][q * 4] = *(const f32x4*)&Pg[(size_t)(trw * 4 + i) * NM + tc * 16 + q * 4];

  auto rowpass = [&]() {
#pragma unroll
    for (int i = 0; i < 4; ++i) {
      float s = p[i][0];
#pragma unroll
      for (int j = 1; j < 16; ++j) s += p[i][j];
      s += __shfl_xor(s, 1);
      s += __shfl_xor(s, 2);
      s += __shfl_xor(s, 4);
      s += __shfl_xor(s, 8);
      const float sc = MASSF / s;
#pragma unroll
      for (int j = 0; j < 16; ++j) p[i][j] *= sc;
    }
  };
  auto colpass = [&]() {
    float tmp[16];
#pragma unroll
    for (int j = 0; j < 16; ++j) tmp[j] = ((p[0][j] + p[1][j]) + (p[2][j] + p[3][j]));
#pragma unroll
    for (int j = 0; j < 16; ++j) {
      tmp[j] += __shfl_xor(tmp[j], 16);
      tmp[j] += __shfl_xor(tmp[j], 32);
    }
    if (l < 16) {
#pragma unroll
      for (int q = 0; q < 4; ++q)
        *(f32x4*)&red[wv][l * 16 + q * 4] = *(const f32x4*)&tmp[q * 4];
    }
    __syncthreads();
    if (t < 256) {
      float s = red[0][t];
#pragma unroll
      for (int w = 1; w < 16; ++w) s += red[w][t];
      scal[t] = MASSF / s;
    }
    __syncthreads();
#pragma unroll
    for (int j = 0; j < 16; ++j) {
      const float sc = scal[tc * 16 + j];
#pragma unroll
      for (int i = 0; i < 4; ++i) p[i][j] *= sc;
    }
    __syncthreads();
  };
  for (int it = 0; it < 7; ++it) {
    rowpass();
    colpass();
  }
  rowpass();
#pragma unroll
  for (int i = 0; i < 4; ++i)
#pragma unroll
    for (int q = 0; q < 4; ++q)
      *(f32x4*)&Pg[(size_t)(trw * 4 + i) * NM + tc * 16 + q * 4] = *(const f32x4*)&p[i][q * 4];
}

extern "C" void kernel_launch(void* const* d_in, const int* in_sizes, int n_in, void* d_out,
                              int out_size, void* d_ws, size_t ws_size, hipStream_t stream) {
  const float* tra_x = (const float*)d_in[0];
  const float* det_x = (const float*)d_in[1];
  const float* W_enc = (const float*)d_in[2];
  const float* b_enc = (const float*)d_in[3];
  const float* W1 = (const float*)d_in[4];
  const float* b1 = (const float*)d_in[5];
  const float* W2 = (const float*)d_in[6];
  const float* b2 = (const float*)d_in[7];
  const float* eps = (const float*)d_in[8];
  float* out = (float*)d_out;

  const size_t SZ = (size_t)NR * ND;
  float* h = (float*)d_ws;         // SZ fp32
  f16* hf = (f16*)(h + SZ);        // SZ f16 (reused per s2)
  f16* baseb = hf + SZ;            // 2*SZ f16
  f16* n1b = baseb + 2 * SZ;       // 2*SZ f16
  f16* featT = n1b + 2 * SZ;       // SZ
  f16* featD = featT + SZ;         // SZ (contiguous with featT)
  float* sq = (float*)(featD + SZ);
  float* nT = sq + NR;             // NR ; nD contiguous
  float* nD = nT + NR;
  int* idx = (int*)(nD + NR);      // 2*NR*NK
  f16* w2t = (f16*)(idx + 2 * (size_t)NR * NK);
  f16* w1cat = w2t + 256 * 256;
  float* biascat = (float*)(w1cat + 512 * 256);
  float* S = out;  // gram scratch lives in d_out until cost overwrites it

  const float* xs[2] = {tra_x, det_x};

  prep_k<<<768, 256, 0, stream>>>(W1, b1, W2, w2t, w1cat, biascat);
  for (int s2 = 0; s2 < 2; ++s2) {
    gemm_nn2_k<<<dim3(2, 256), 256, 0, stream>>>(xs[s2], W_enc, b_enc, h, hf);
    mlp1_mfma_k<<<dim3(4, 256), 256, 0, stream>>>(hf, w1cat, biascat, baseb + s2 * SZ,
                                                  n1b + s2 * SZ);
    gemm_nt2_k<<<dim3(2, 4, NG), 256, 0, stream>>>(h, S, sq);
    topk_k<<<4096, 256, 0, stream>>>(S, sq, idx + (size_t)s2 * NR * NK);
  }
  edgemlp_mfma10_k<<<1024, 512, 0, stream>>>(baseb, n1b, idx, w2t, b2, featT, nT);
  cost_mfma_k<<<512, 256, 0, stream>>>(featT, featD, nT, nD, eps, out);
  sinkhorn_k<<<NG, 1024, 0, stream>>>(out);
}

// Round 14
// 369.775 us; speedup vs baseline: 1.1887x; 1.0053x over previous
//
#include <hip/hip_runtime.h>
#include <math.h>

#define NG 64
#define NM 256
#define ND 256
#define NK 16
#define NR (NG * NM)  // 16384 rows total
#define NB 32         // nodes per edge-MLP block

#define MASSF 0.9f

typedef _Float16 f16;
typedef __attribute__((ext_vector_type(8))) _Float16 f16x8;
typedef __attribute__((ext_vector_type(4))) _Float16 f16x4;
typedef __attribute__((ext_vector_type(4))) float f32x4;
typedef __attribute__((ext_vector_type(4))) unsigned u32x4;

// packed relu(a+b) on 2xf16
static __device__ __forceinline__ unsigned pkrelu(unsigned a, unsigned b) {
  unsigned r;
  asm("v_pk_add_f16 %0, %1, %2" : "=v"(r) : "v"(a), "v"(b));
  asm("v_pk_max_f16 %0, %1, %2" : "=v"(r) : "v"(r), "v"(0u));
  return r;
}

// ---------------- prep: W2^T (f16), W1cat = [W1hi - W1lo ; W1lo]^T (f16) ------
__global__ __launch_bounds__(256) void prep_k(const float* __restrict__ W1,
                                              const float* __restrict__ b1,
                                              const float* __restrict__ W2,
                                              f16* __restrict__ w2t, f16* __restrict__ w1cat,
                                              float* __restrict__ biascat) {
  const int b = blockIdx.x, k = threadIdx.x;
  if (b < 256) {
    w2t[b * 256 + k] = (f16)W2[(size_t)k * 256 + b];
  } else {
    const int n = b - 256;  // 0..511
    float v;
    if (n < 256)
      v = W1[(size_t)k * 256 + n] - W1[(size_t)(k + 256) * 256 + n];
    else
      v = W1[(size_t)(k + 256) * 256 + (n - 256)];
    w1cat[(size_t)n * 256 + k] = (f16)v;
    if (k == 0) biascat[n] = (n < 256) ? b1[n] : 0.f;
  }
}

// ---- encoder GEMM fp32, merged over both inputs: h2[half] = relu(x@W+b) -----
// 64x128 tile, 4x8 split micro-tile, dbuf LDS (round-10 proven structure).
__global__ __launch_bounds__(256) void gemm_nn2m_k(const float* __restrict__ A0,
                                                   const float* __restrict__ A1,
                                                   const float* __restrict__ B,
                                                   const float* __restrict__ bias,
                                                   float* __restrict__ h2) {
  __shared__ float As[2][16][68];
  __shared__ float Bs[2][16][128];
  const int tid = threadIdx.x;
  const int tx = tid & 15, ty = tid >> 4;
  const int half = blockIdx.y >> 8;
  const int m0 = (blockIdx.y & 255) * 64, n0 = blockIdx.x * 128;
  const float* A = half ? A1 : A0;
  float* C = h2 + (size_t)half * NR * ND;
  const int arow = tid >> 2, akc = (tid & 3) * 4;
  const int bkr = tid >> 4, bcc = (tid & 15) * 4;
  float4 av, bv0, bv1;
  float acc[4][8] = {};
  auto gload = [&](int k0) {
    av = *(const float4*)&A[(size_t)(m0 + arow) * 256 + k0 + akc];
    bv0 = *(const float4*)&B[(size_t)(k0 + bkr) * 256 + n0 + bcc];
    bv1 = *(const float4*)&B[(size_t)(k0 + bkr) * 256 + n0 + 64 + bcc];
  };
  auto swrite = [&](int buf) {
    As[buf][akc + 0][arow] = av.x;
    As[buf][akc + 1][arow] = av.y;
    As[buf][akc + 2][arow] = av.z;
    As[buf][akc + 3][arow] = av.w;
    *(float4*)&Bs[buf][bkr][bcc] = bv0;
    *(float4*)&Bs[buf][bkr][64 + bcc] = bv1;
  };
  gload(0);
  swrite(0);
  __syncthreads();
  for (int s = 0; s < 16; ++s) {
    if (s < 15) gload((s + 1) * 16);
    const int buf = s & 1;
#pragma unroll
    for (int kk = 0; kk < 16; ++kk) {
      const float4 a0 = *(const float4*)&As[buf][kk][ty * 4];
      const float4 b0 = *(const float4*)&Bs[buf][kk][tx * 4];
      const float4 b1 = *(const float4*)&Bs[buf][kk][64 + tx * 4];
      const float aa[4] = {a0.x, a0.y, a0.z, a0.w};
      const float bb[8] = {b0.x, b0.y, b0.z, b0.w, b1.x, b1.y, b1.z, b1.w};
#pragma unroll
      for (int i = 0; i < 4; ++i)
#pragma unroll
        for (int j = 0; j < 8; ++j) acc[i][j] = fmaf(aa[i], bb[j], acc[i][j]);
    }
    if (s < 15) swrite((s + 1) & 1);
    __syncthreads();
  }
  const float4 bia0 = *(const float4*)&bias[n0 + tx * 4];
  const float4 bia1 = *(const float4*)&bias[n0 + 64 + tx * 4];
#pragma unroll
  for (int i = 0; i < 4; ++i) {
    const size_t row = (size_t)(m0 + ty * 4 + i);
    float4 o0 = {fmaxf(acc[i][0] + bia0.x, 0.f), fmaxf(acc[i][1] + bia0.y, 0.f),
                 fmaxf(acc[i][2] + bia0.z, 0.f), fmaxf(acc[i][3] + bia0.w, 0.f)};
    float4 o1 = {fmaxf(acc[i][4] + bia1.x, 0.f), fmaxf(acc[i][5] + bia1.y, 0.f),
                 fmaxf(acc[i][6] + bia1.z, 0.f), fmaxf(acc[i][7] + bia1.w, 0.f)};
    *(float4*)&C[row * 256 + n0 + tx * 4] = o0;
    *(float4*)&C[row * 256 + n0 + 64 + tx * 4] = o1;
  }
}

// ---------------- symmetric gram NT fp32 per graph + fused diagonal ----------
__global__ __launch_bounds__(256) void gemm_nt2_k(const float* __restrict__ h,
                                                  float* __restrict__ C,
                                                  float* __restrict__ sq) {
  const int flat0 = blockIdx.x + 2 * (blockIdx.y + 4 * blockIdx.z);
  const int flat = ((flat0 & 7) << 6) | (flat0 >> 3);  // 512 blocks: %8 *64 + /8
  const int bx = flat & 1, by = (flat >> 1) & 3, g = flat >> 3;
  if (bx == 0 && by >= 2) return;  // covered by mirror of (bx=1, by<2)
  __shared__ float As[2][16][68];
  __shared__ float Bs[2][16][128];
  const float* Ag = h + (size_t)g * NM * ND;
  float* Cg = C + (size_t)g * NM * NM;
  const int tid = threadIdx.x;
  const int tx = tid & 15, ty = tid >> 4;
  const int m0 = by * 64, n0 = bx * 128;
  const int arow = tid >> 2, akc = (tid & 3) * 4;
  const int brow = tid >> 1, bkc = (tid & 1) * 8;
  float4 av, bva, bvb;
  float acc[4][8] = {};
  auto gload = [&](int k0) {
    av = *(const float4*)&Ag[(size_t)(m0 + arow) * 256 + k0 + akc];
    bva = *(const float4*)&Ag[(size_t)(n0 + brow) * 256 + k0 + bkc];
    bvb = *(const float4*)&Ag[(size_t)(n0 + brow) * 256 + k0 + bkc + 4];
  };
  auto swrite = [&](int buf) {
    As[buf][akc + 0][arow] = av.x;
    As[buf][akc + 1][arow] = av.y;
    As[buf][akc + 2][arow] = av.z;
    As[buf][akc + 3][arow] = av.w;
    Bs[buf][bkc + 0][brow] = bva.x;
    Bs[buf][bkc + 1][brow] = bva.y;
    Bs[buf][bkc + 2][brow] = bva.z;
    Bs[buf][bkc + 3][brow] = bva.w;
    Bs[buf][bkc + 4][brow] = bvb.x;
    Bs[buf][bkc + 5][brow] = bvb.y;
    Bs[buf][bkc + 6][brow] = bvb.z;
    Bs[buf][bkc + 7][brow] = bvb.w;
  };
  gload(0);
  swrite(0);
  __syncthreads();
  for (int s = 0; s < 16; ++s) {
    if (s < 15) gload((s + 1) * 16);
    const int buf = s & 1;
#pragma unroll
    for (int kk = 0; kk < 16; ++kk) {
      const float4 a0 = *(const float4*)&As[buf][kk][ty * 4];
      const float4 b0 = *(const float4*)&Bs[buf][kk][tx * 4];
      const float4 b1 = *(const float4*)&Bs[buf][kk][64 + tx * 4];
      const float aa[4] = {a0.x, a0.y, a0.z, a0.w};
      const float bb[8] = {b0.x, b0.y, b0.z, b0.w, b1.x, b1.y, b1.z, b1.w};
#pragma unroll
      for (int i = 0; i < 4; ++i)
#pragma unroll
        for (int j = 0; j < 8; ++j) acc[i][j] = fmaf(aa[i], bb[j], acc[i][j]);
    }
    if (s < 15) swrite((s + 1) & 1);
    __syncthreads();
  }
  const int c0 = n0 + tx * 4, c1 = n0 + 64 + tx * 4;
#pragma unroll
  for (int i = 0; i < 4; ++i) {
    const int row = m0 + ty * 4 + i;
    float4 o0 = {acc[i][0], acc[i][1], acc[i][2], acc[i][3]};
    float4 o1 = {acc[i][4], acc[i][5], acc[i][6], acc[i][7]};
    *(float4*)&Cg[(size_t)row * 256 + c0] = o0;
    *(float4*)&Cg[(size_t)row * 256 + c1] = o1;
    if (row >= c0 && row < c0 + 4) sq[g * 256 + row] = acc[i][row - c0];
    if (row >= c1 && row < c1 + 4) sq[g * 256 + row] = acc[i][4 + row - c1];
  }
  if (bx == 1 && by < 2) {  // mirror into the skipped lower-left region
#pragma unroll
    for (int j = 0; j < 4; ++j) {
      const size_t col0 = (size_t)(n0 + tx * 4 + j);
      const size_t col1 = (size_t)(n0 + 64 + tx * 4 + j);
      float4 t0 = {acc[0][j], acc[1][j], acc[2][j], acc[3][j]};
      float4 t1 = {acc[0][4 + j], acc[1][4 + j], acc[2][4 + j], acc[3][4 + j]};
      *(float4*)&Cg[col0 * 256 + m0 + ty * 4] = t0;
      *(float4*)&Cg[col1 * 256 + m0 + ty * 4] = t1;
    }
  }
}

// -- MFMA GEMM merged: [2][16384,256] fp32 h @ w1cat^T -> baseb2, n1b2 (f16) ---
// Staging converts fp32 h -> f16 in-register (same values the old hf held).
__global__ __launch_bounds__(256, 2) void mlp1m_mfma_k(const float* __restrict__ h2,
                                                       const f16* __restrict__ Bt,
                                                       const float* __restrict__ biascat,
                                                       f16* __restrict__ baseb2,
                                                       f16* __restrict__ n1b2) {
  __shared__ char As[64 * 512];
  const int tid = threadIdx.x;
  const int l = tid & 63, wv = tid >> 6;
  const int r = l & 15, gq = l >> 4;
  const int half = blockIdx.y >> 8;
  const int m0 = (blockIdx.y & 255) * 64, n0 = blockIdx.x * 128;
  const float* A = h2 + (size_t)half * NR * ND;
  f16x8 bfr[2][8];
  float bv[2];
#pragma unroll
  for (int nt = 0; nt < 2; ++nt) {
    const int col = n0 + wv * 32 + nt * 16 + r;
    const f16* wb = Bt + (size_t)col * 256 + gq * 8;
#pragma unroll
    for (int ks = 0; ks < 8; ++ks) bfr[nt][ks] = *(const f16x8*)(wb + ks * 32);
    bv[nt] = biascat[col];
  }
  const int row = tid >> 2, ch = tid & 3;
  const float* ag = A + (size_t)(m0 + row) * 256 + ch * 64;
  char* lb = As + row * 512;
#pragma unroll
  for (int j = 0; j < 8; ++j) {
    const float4 x0 = *(const float4*)(ag + j * 8);
    const float4 x1 = *(const float4*)(ag + j * 8 + 4);
    f16x8 w = {(f16)x0.x, (f16)x0.y, (f16)x0.z, (f16)x0.w,
               (f16)x1.x, (f16)x1.y, (f16)x1.z, (f16)x1.w};
    *(f16x8*)(lb + (((ch * 128 + j * 16)) ^ ((row & 7) << 4))) = w;
  }
  __syncthreads();
  f32x4 acc[4][2];
#pragma unroll
  for (int mt = 0; mt < 4; ++mt)
#pragma unroll
    for (int nt = 0; nt < 2; ++nt) acc[mt][nt] = (f32x4){0.f, 0.f, 0.f, 0.f};
#pragma unroll
  for (int ks = 0; ks < 8; ++ks) {
    f16x8 a[4];
#pragma unroll
    for (int mt = 0; mt < 4; ++mt)
      a[mt] = *(const f16x8*)(As + (mt * 16 + r) * 512 + ((gq * 16 + ks * 64) ^ ((r & 7) << 4)));
#pragma unroll
    for (int mt = 0; mt < 4; ++mt)
#pragma unroll
      for (int nt = 0; nt < 2; ++nt)
        acc[mt][nt] = __builtin_amdgcn_mfma_f32_16x16x32_f16(a[mt], bfr[nt][ks], acc[mt][nt], 0, 0, 0);
  }
  f16* dst = ((n0 < 256) ? baseb2 : n1b2) + (size_t)half * NR * ND;
  const int cb = (n0 < 256) ? n0 : n0 - 256;
#pragma unroll
  for (int mt = 0; mt < 4; ++mt)
#pragma unroll
    for (int nt = 0; nt < 2; ++nt) {
      const int col = cb + wv * 32 + nt * 16 + r;
#pragma unroll
      for (int reg = 0; reg < 4; ++reg) {
        const int rw = m0 + mt * 16 + gq * 4 + reg;
        dst[(size_t)rw * 256 + col] = (f16)(acc[mt][nt][reg] + bv[nt]);
      }
    }
}

// ---------------- MFMA cost GEMM -> P0 = exp(corr/(nA nB lam)), XCD-swizzled --
__global__ __launch_bounds__(256, 2) void cost_mfma_k(const f16* __restrict__ featT,
                                                      const f16* __restrict__ featD,
                                                      const float* __restrict__ nA,
                                                      const float* __restrict__ nB,
                                                      const float* __restrict__ eps,
                                                      float* __restrict__ P) {
  __shared__ char As[64 * 512];
  const int flat = ((blockIdx.x & 7) << 6) | (blockIdx.x >> 3);
  const int bx = flat & 1, by = (flat >> 1) & 3, g = flat >> 3;
  const f16* A = featT + (size_t)g * NM * ND;
  const f16* Bt = featD + (size_t)g * NM * ND;
  const int tid = threadIdx.x;
  const int l = tid & 63, wv = tid >> 6;
  const int r = l & 15, gq = l >> 4;
  const int m0 = by * 64, n0 = bx * 128;
  f16x8 bfr[2][8];
  float rnb[2];
#pragma unroll
  for (int nt = 0; nt < 2; ++nt) {
    const int col = n0 + wv * 32 + nt * 16 + r;
    const f16* wb = Bt + (size_t)col * 256 + gq * 8;
#pragma unroll
    for (int ks = 0; ks < 8; ++ks) bfr[nt][ks] = *(const f16x8*)(wb + ks * 32);
    rnb[nt] = 1.0f / nB[g * NM + col];
  }
  const int row = tid >> 2, ch = tid & 3;
  const char* ag = (const char*)(A + (size_t)(m0 + row) * 256) + ch * 128;
  char* lb = As + row * 512;
#pragma unroll
  for (int j = 0; j < 8; ++j)
    *(f16x8*)(lb + (((ch * 128 + j * 16)) ^ ((row & 7) << 4))) = *(const f16x8*)(ag + j * 16);
  __syncthreads();
  f32x4 acc[4][2];
#pragma unroll
  for (int mt = 0; mt < 4; ++mt)
#pragma unroll
    for (int nt = 0; nt < 2; ++nt) acc[mt][nt] = (f32x4){0.f, 0.f, 0.f, 0.f};
#pragma unroll
  for (int ks = 0; ks < 8; ++ks) {
    f16x8 a[4];
#pragma unroll
    for (int mt = 0; mt < 4; ++mt)
      a[mt] = *(const f16x8*)(As + (mt * 16 + r) * 512 + ((gq * 16 + ks * 64) ^ ((r & 7) << 4)));
#pragma unroll
    for (int mt = 0; mt < 4; ++mt)
#pragma unroll
      for (int nt = 0; nt < 2; ++nt)
        acc[mt][nt] = __builtin_amdgcn_mfma_f32_16x16x32_f16(a[mt], bfr[nt][ks], acc[mt][nt], 0, 0, 0);
  }
  const float inv_lam = 1.0f / (expf(eps[0]) + 0.03f);
#pragma unroll
  for (int mt = 0; mt < 4; ++mt) {
    float ria[4];
#pragma unroll
    for (int reg = 0; reg < 4; ++reg)
      ria[reg] = inv_lam / nA[g * NM + m0 + mt * 16 + gq * 4 + reg];
#pragma unroll
    for (int nt = 0; nt < 2; ++nt) {
      const int col = n0 + wv * 32 + nt * 16 + r;
#pragma unroll
      for (int reg = 0; reg < 4; ++reg) {
        const int rw = m0 + mt * 16 + gq * 4 + reg;
        P[(size_t)g * NM * NM + (size_t)rw * 256 + col] =
            expf(acc[mt][nt][reg] * ria[reg] * rnb[nt]);
      }
    }
  }
}

// ---------------- top-16 nearest neighbors (wave per row) ----------------
__global__ __launch_bounds__(256) void topk_k(const float* __restrict__ S,
                                              const float* __restrict__ sq,
                                              int* __restrict__ idx) {
  const int w = threadIdx.x >> 6, lane = threadIdx.x & 63;
  const int row = blockIdx.x * 4 + w;
  const int g = row >> 8, m = row & 255;
  const float* Srow = S + (size_t)row * NM;
  const float* sqg = sq + g * NM;
  const float sm = sqg[m];
  const float4 sv = *(const float4*)&Srow[lane * 4];
  const float4 qv = *(const float4*)&sqg[lane * 4];
  float cand[4] = {sm + qv.x - 2.f * sv.x, sm + qv.y - 2.f * sv.y, sm + qv.z - 2.f * sv.z,
                   sm + qv.w - 2.f * sv.w};
#pragma unroll
  for (int t = 0; t < 4; ++t)
    if (lane * 4 + t == m) cand[t] = 1e30f;
  for (int rnd = 0; rnd < NK; ++rnd) {
    float bvv = cand[0];
    int bi = lane * 4;
#pragma unroll
    for (int t = 1; t < 4; ++t)
      if (cand[t] < bvv) {
        bvv = cand[t];
        bi = lane * 4 + t;
      }
#pragma unroll
    for (int off = 1; off < 64; off <<= 1) {
      const float ov = __shfl_xor(bvv, off);
      const int oi = __shfl_xor(bi, off);
      if (ov < bvv || (ov == bvv && oi < bi)) {
        bvv = ov;
        bi = oi;
      }
    }
    if (lane == 0) idx[(size_t)row * NK + rnd] = bi;
    if ((bi >> 2) == lane) cand[bi & 3] = 1e30f;
  }
}

// --------- edge MLP v10: v8 structure, merged over both graph-convs ----------
__global__ __launch_bounds__(512, 4) void edgemlp_mfma10_k(
    const f16* __restrict__ baseb2, const f16* __restrict__ n1b2, const int* __restrict__ idx2,
    const f16* __restrict__ w2t, const float* __restrict__ b2, f16* __restrict__ featf2,
    float* __restrict__ nrm2) {
  __shared__ unsigned E[2][2][512 * 4];  // [buf][node-in-pair][slot*4u] = 32 KB
  __shared__ int sidx[NB * NK];          // 512 ints
  __shared__ float normp[NB][8];
  const int tid = threadIdx.x;
  const int l = tid & 63, wv = tid >> 6;
  const size_t SZH = (size_t)NR * ND;
  const int bid = blockIdx.x;  // 0..1023
  const int half = bid >> 9;
  const int b9 = bid & 511;
  const int blk = ((b9 & 7) << 6) | (b9 >> 3);  // XCD: 8 graphs each
  const int node0 = blk * NB;
  const int g = node0 >> 8;
  const f16* baseb = baseb2 + (size_t)half * SZH;
  const f16* n1b = n1b2 + (size_t)half * SZH;
  const int* idx = idx2 + (size_t)half * NR * NK;
  f16* featf = featf2 + (size_t)half * SZH;
  float* nrm = nrm2 + (size_t)half * NR;
  const int r = l & 15, gq = l >> 4;
  sidx[tid] = idx[(size_t)node0 * NK + tid];
  f16x8 bfr[2][8];
  float b2v[2];
#pragma unroll
  for (int t = 0; t < 2; ++t) {
    const int nb = wv * 2 + t;
    const f16* wb = w2t + (size_t)(nb * 16 + r) * 256 + gq * 8;
#pragma unroll
    for (int ks = 0; ks < 8; ++ks) bfr[t][ks] = *(const f16x8*)(wb + ks * 32);
    b2v[t] = b2[nb * 16 + r];
  }
  __syncthreads();  // sidx visible
  const int r_s = tid & 15;
  const int col_s = ((tid >> 6) * 32) + (((tid >> 4) & 3) * 8);
  u32x4 bs0, ns0, bs1, ns1;
  auto sload = [&](int s) {
    const int na = s * 2;
    bs0 = *(const u32x4*)(baseb + (((size_t)(node0 + na)) << 8) + col_s);
    ns0 = *(const u32x4*)(n1b + ((((size_t)g << 8) + sidx[na * NK + r_s]) << 8) + col_s);
    bs1 = *(const u32x4*)(baseb + (((size_t)(node0 + na + 1)) << 8) + col_s);
    ns1 = *(const u32x4*)(n1b + ((((size_t)g << 8) + sidx[(na + 1) * NK + r_s]) << 8) + col_s);
  };
  auto swrite = [&](int s) {
    const int buf = s & 1;
    u32x4 w0, w1;
#pragma unroll
    for (int q = 0; q < 4; ++q) {
      w0[q] = pkrelu(bs0[q], ns0[q]);
      w1[q] = pkrelu(bs1[q], ns1[q]);
    }
    *(u32x4*)&E[buf][0][tid * 4] = w0;
    *(u32x4*)&E[buf][1][tid * 4] = w1;
  };
  sload(0);
  swrite(0);
  __syncthreads();
  for (int s = 0; s < NB / 2; ++s) {
    if (s + 1 < NB / 2) sload(s + 1);
    const int buf = s & 1;
#pragma unroll
    for (int q = 0; q < 2; ++q) {
      const char* eb = (const char*)&E[buf][q][0];
      f32x4 acc0 = (f32x4){0.f, 0.f, 0.f, 0.f};
      f32x4 acc1 = (f32x4){0.f, 0.f, 0.f, 0.f};
#pragma unroll
      for (int ks = 0; ks < 8; ++ks) {
        const f16x8 a = *(const f16x8*)(eb + ks * 1024 + l * 16);
        acc0 = __builtin_amdgcn_mfma_f32_16x16x32_f16(a, bfr[0][ks], acc0, 0, 0, 0);
        acc1 = __builtin_amdgcn_mfma_f32_16x16x32_f16(a, bfr[1][ks], acc1, 0, 0, 0);
      }
      const int nd = node0 + s * 2 + q;
      float m0v = fmaxf(fmaxf(acc0[0], acc0[1]), fmaxf(acc0[2], acc0[3]));
      m0v = fmaxf(m0v, __shfl_xor(m0v, 16));
      m0v = fmaxf(m0v, __shfl_xor(m0v, 32));
      float m1v = fmaxf(fmaxf(acc1[0], acc1[1]), fmaxf(acc1[2], acc1[3]));
      m1v = fmaxf(m1v, __shfl_xor(m1v, 16));
      m1v = fmaxf(m1v, __shfl_xor(m1v, 32));
      const f16 h0 = (f16)(m0v + b2v[0]);
      const f16 h1 = (f16)(m1v + b2v[1]);
      if (gq == 0) {
        featf[((size_t)nd << 8) + (wv * 2 + 0) * 16 + r] = h0;
        featf[((size_t)nd << 8) + (wv * 2 + 1) * 16 + r] = h1;
      }
      const float o0 = (float)h0, o1 = (float)h1;
      float ss = o0 * o0 + o1 * o1;
      ss += __shfl_xor(ss, 1);
      ss += __shfl_xor(ss, 2);
      ss += __shfl_xor(ss, 4);
      ss += __shfl_xor(ss, 8);
      if (l == 0) normp[s * 2 + q][wv] = ss;
    }
    if (s + 1 < NB / 2) swrite(s + 1);
    __syncthreads();
  }
  if (tid < NB) {
    float s = 0.f;
#pragma unroll
    for (int w = 0; w < 8; ++w) s += normp[tid][w];
    nrm[node0 + tid] = sqrtf(s);
  }
}

// ---------------- fused Sinkhorn, plain domain: block per graph, P in regs ----
__global__ __launch_bounds__(1024) void sinkhorn_k(float* __restrict__ P) {
  __shared__ float red[16][256];
  __shared__ float scal[256];
  const int t = threadIdx.x;
  const int tc = t & 15;
  const int trw = t >> 4;
  const int wv = t >> 6, l = t & 63;
  float* Pg = P + (size_t)blockIdx.x * NM * NM;
  float p[4][16];
#pragma unroll
  for (int i = 0; i < 4; ++i)
#pragma unroll
    for (int q = 0; q < 4; ++q)
      *(f32x4*)&p[i][q * 4] = *(const f32x4*)&Pg[(size_t)(trw * 4 + i) * NM + tc * 16 + q * 4];

  auto rowpass = [&]() {
#pragma unroll
    for (int i = 0; i < 4; ++i) {
      float s = p[i][0];
#pragma unroll
      for (int j = 1; j < 16; ++j) s += p[i][j];
      s += __shfl_xor(s, 1);
      s += __shfl_xor(s, 2);
      s += __shfl_xor(s, 4);
      s += __shfl_xor(s, 8);
      const float sc = MASSF / s;
#pragma unroll
      for (int j = 0; j < 16; ++j) p[i][j] *= sc;
    }
  };
  auto colpass = [&]() {
    float tmp[16];
#pragma unroll
    for (int j = 0; j < 16; ++j) tmp[j] = ((p[0][j] + p[1][j]) + (p[2][j] + p[3][j]));
#pragma unroll
    for (int j = 0; j < 16; ++j) {
      tmp[j] += __shfl_xor(tmp[j], 16);
      tmp[j] += __shfl_xor(tmp[j], 32);
    }
    if (l < 16) {
#pragma unroll
      for (int q = 0; q < 4; ++q)
        *(f32x4*)&red[wv][l * 16 + q * 4] = *(const f32x4*)&tmp[q * 4];
    }
    __syncthreads();
    if (t < 256) {
      float s = red[0][t];
#pragma unroll
      for (int w = 1; w < 16; ++w) s += red[w][t];
      scal[t] = MASSF / s;
    }
    __syncthreads();
#pragma unroll
    for (int j = 0; j < 16; ++j) {
      const float sc = scal[tc * 16 + j];
#pragma unroll
      for (int i = 0; i < 4; ++i) p[i][j] *= sc;
    }
    __syncthreads();
  };
  for (int it = 0; it < 7; ++it) {
    rowpass();
    colpass();
  }
  rowpass();
#pragma unroll
  for (int i = 0; i < 4; ++i)
#pragma unroll
    for (int q = 0; q < 4; ++q)
      *(f32x4*)&Pg[(size_t)(trw * 4 + i) * NM + tc * 16 + q * 4] = *(const f32x4*)&p[i][q * 4];
}

extern "C" void kernel_launch(void* const* d_in, const int* in_sizes, int n_in, void* d_out,
                              int out_size, void* d_ws, size_t ws_size, hipStream_t stream) {
  const float* tra_x = (const float*)d_in[0];
  const float* det_x = (const float*)d_in[1];
  const float* W_enc = (const float*)d_in[2];
  const float* b_enc = (const float*)d_in[3];
  const float* W1 = (const float*)d_in[4];
  const float* b1 = (const float*)d_in[5];
  const float* W2 = (const float*)d_in[6];
  const float* b2 = (const float*)d_in[7];
  const float* eps = (const float*)d_in[8];
  float* out = (float*)d_out;

  const size_t SZ = (size_t)NR * ND;
  float* h2 = (float*)d_ws;        // 2*SZ fp32
  f16* baseb = (f16*)(h2 + 2 * SZ);  // 2*SZ f16
  f16* n1b = baseb + 2 * SZ;       // 2*SZ f16
  f16* featT = n1b + 2 * SZ;       // SZ
  f16* featD = featT + SZ;         // SZ (contiguous with featT)
  float* sq = (float*)(featD + SZ);
  float* nT = sq + NR;             // NR ; nD contiguous
  float* nD = nT + NR;
  int* idx = (int*)(nD + NR);      // 2*NR*NK
  f16* w2t = (f16*)(idx + 2 * (size_t)NR * NK);
  f16* w1cat = w2t + 256 * 256;
  float* biascat = (float*)(w1cat + 512 * 256);
  float* S = out;  // gram scratch lives in d_out until cost overwrites it

  prep_k<<<768, 256, 0, stream>>>(W1, b1, W2, w2t, w1cat, biascat);
  gemm_nn2m_k<<<dim3(2, 512), 256, 0, stream>>>(tra_x, det_x, W_enc, b_enc, h2);
  mlp1m_mfma_k<<<dim3(4, 512), 256, 0, stream>>>(h2, w1cat, biascat, baseb, n1b);
  for (int s2 = 0; s2 < 2; ++s2) {
    gemm_nt2_k<<<dim3(2, 4, NG), 256, 0, stream>>>(h2 + s2 * SZ, S, sq);
    topk_k<<<4096, 256, 0, stream>>>(S, sq, idx + (size_t)s2 * NR * NK);
  }
  edgemlp_mfma10_k<<<1024, 512, 0, stream>>>(baseb, n1b, idx, w2t, b2, featT, nT);
  cost_mfma_k<<<512, 256, 0, stream>>>(featT, featD, nT, nD, eps, out);
  sinkhorn_k<<<NG, 1024, 0, stream>>>(out);
}

// Round 15
// 354.891 us; speedup vs baseline: 1.2385x; 1.0419x over previous
//
#include <hip/hip_runtime.h>
#include <math.h>

#define NG 64
#define NM 256
#define ND 256
#define NK 16
#define NR (NG * NM)  // 16384 rows total
#define NB 32         // nodes per edge-MLP block

#define MASSF 0.9f

typedef _Float16 f16;
typedef __attribute__((ext_vector_type(8))) _Float16 f16x8;
typedef __attribute__((ext_vector_type(4))) _Float16 f16x4;
typedef __attribute__((ext_vector_type(4))) float f32x4;
typedef __attribute__((ext_vector_type(4))) unsigned u32x4;

// packed relu(a+b) on 2xf16
static __device__ __forceinline__ unsigned pkrelu(unsigned a, unsigned b) {
  unsigned r;
  asm("v_pk_add_f16 %0, %1, %2" : "=v"(r) : "v"(a), "v"(b));
  asm("v_pk_max_f16 %0, %1, %2" : "=v"(r) : "v"(r), "v"(0u));
  return r;
}

// ---------------- prep: W2^T (f16), W1cat = [W1hi - W1lo ; W1lo]^T (f16) ------
__global__ __launch_bounds__(256) void prep_k(const float* __restrict__ W1,
                                              const float* __restrict__ b1,
                                              const float* __restrict__ W2,
                                              f16* __restrict__ w2t, f16* __restrict__ w1cat,
                                              float* __restrict__ biascat) {
  const int b = blockIdx.x, k = threadIdx.x;
  if (b < 256) {
    w2t[b * 256 + k] = (f16)W2[(size_t)k * 256 + b];
  } else {
    const int n = b - 256;  // 0..511
    float v;
    if (n < 256)
      v = W1[(size_t)k * 256 + n] - W1[(size_t)(k + 256) * 256 + n];
    else
      v = W1[(size_t)(k + 256) * 256 + (n - 256)];
    w1cat[(size_t)n * 256 + k] = (f16)v;
    if (k == 0) biascat[n] = (n < 256) ? b1[n] : 0.f;
  }
}

// ---- encoder GEMM fp32, merged over both inputs: h2[half] = relu(x@W+b) -----
__global__ __launch_bounds__(256) void gemm_nn2m_k(const float* __restrict__ A0,
                                                   const float* __restrict__ A1,
                                                   const float* __restrict__ B,
                                                   const float* __restrict__ bias,
                                                   float* __restrict__ h2) {
  __shared__ float As[2][16][68];
  __shared__ float Bs[2][16][128];
  const int tid = threadIdx.x;
  const int tx = tid & 15, ty = tid >> 4;
  const int half = blockIdx.y >> 8;
  const int m0 = (blockIdx.y & 255) * 64, n0 = blockIdx.x * 128;
  const float* A = half ? A1 : A0;
  float* C = h2 + (size_t)half * NR * ND;
  const int arow = tid >> 2, akc = (tid & 3) * 4;
  const int bkr = tid >> 4, bcc = (tid & 15) * 4;
  float4 av, bv0, bv1;
  float acc[4][8] = {};
  auto gload = [&](int k0) {
    av = *(const float4*)&A[(size_t)(m0 + arow) * 256 + k0 + akc];
    bv0 = *(const float4*)&B[(size_t)(k0 + bkr) * 256 + n0 + bcc];
    bv1 = *(const float4*)&B[(size_t)(k0 + bkr) * 256 + n0 + 64 + bcc];
  };
  auto swrite = [&](int buf) {
    As[buf][akc + 0][arow] = av.x;
    As[buf][akc + 1][arow] = av.y;
    As[buf][akc + 2][arow] = av.z;
    As[buf][akc + 3][arow] = av.w;
    *(float4*)&Bs[buf][bkr][bcc] = bv0;
    *(float4*)&Bs[buf][bkr][64 + bcc] = bv1;
  };
  gload(0);
  swrite(0);
  __syncthreads();
  for (int s = 0; s < 16; ++s) {
    if (s < 15) gload((s + 1) * 16);
    const int buf = s & 1;
#pragma unroll
    for (int kk = 0; kk < 16; ++kk) {
      const float4 a0 = *(const float4*)&As[buf][kk][ty * 4];
      const float4 b0 = *(const float4*)&Bs[buf][kk][tx * 4];
      const float4 b1 = *(const float4*)&Bs[buf][kk][64 + tx * 4];
      const float aa[4] = {a0.x, a0.y, a0.z, a0.w};
      const float bb[8] = {b0.x, b0.y, b0.z, b0.w, b1.x, b1.y, b1.z, b1.w};
#pragma unroll
      for (int i = 0; i < 4; ++i)
#pragma unroll
        for (int j = 0; j < 8; ++j) acc[i][j] = fmaf(aa[i], bb[j], acc[i][j]);
    }
    if (s < 15) swrite((s + 1) & 1);
    __syncthreads();
  }
  const float4 bia0 = *(const float4*)&bias[n0 + tx * 4];
  const float4 bia1 = *(const float4*)&bias[n0 + 64 + tx * 4];
#pragma unroll
  for (int i = 0; i < 4; ++i) {
    const size_t row = (size_t)(m0 + ty * 4 + i);
    float4 o0 = {fmaxf(acc[i][0] + bia0.x, 0.f), fmaxf(acc[i][1] + bia0.y, 0.f),
                 fmaxf(acc[i][2] + bia0.z, 0.f), fmaxf(acc[i][3] + bia0.w, 0.f)};
    float4 o1 = {fmaxf(acc[i][4] + bia1.x, 0.f), fmaxf(acc[i][5] + bia1.y, 0.f),
                 fmaxf(acc[i][6] + bia1.z, 0.f), fmaxf(acc[i][7] + bia1.w, 0.f)};
    *(float4*)&C[row * 256 + n0 + tx * 4] = o0;
    *(float4*)&C[row * 256 + n0 + 64 + tx * 4] = o1;
  }
}

// ---- symmetric gram NT fp32, merged over both halves, fused diagonal --------
// 1024 blocks, XCD-swizzled; half 0 -> S0 (d_out), half 1 -> S1 (scratch).
__global__ __launch_bounds__(256) void gemm_nt2m_k(const float* __restrict__ h2,
                                                   float* __restrict__ S0,
                                                   float* __restrict__ S1,
                                                   float* __restrict__ sq2) {
  const int flat0 = blockIdx.x;                         // 0..1023
  const int flat = ((flat0 & 7) << 7) | (flat0 >> 3);   // XCD: 128 consecutive
  const int half = flat >> 9;
  const int inner = flat & 511;
  const int bx = inner & 1, by = (inner >> 1) & 3, g = inner >> 3;
  if (bx == 0 && by >= 2) return;  // covered by mirror of (bx=1, by<2)
  __shared__ float As[2][16][68];
  __shared__ float Bs[2][16][128];
  const float* Ag = h2 + (size_t)half * NR * ND + (size_t)g * NM * ND;
  float* Cg = (half ? S1 : S0) + (size_t)g * NM * NM;
  float* sq = sq2 + half * NR + g * 256;
  const int tid = threadIdx.x;
  const int tx = tid & 15, ty = tid >> 4;
  const int m0 = by * 64, n0 = bx * 128;
  const int arow = tid >> 2, akc = (tid & 3) * 4;
  const int brow = tid >> 1, bkc = (tid & 1) * 8;
  float4 av, bva, bvb;
  float acc[4][8] = {};
  auto gload = [&](int k0) {
    av = *(const float4*)&Ag[(size_t)(m0 + arow) * 256 + k0 + akc];
    bva = *(const float4*)&Ag[(size_t)(n0 + brow) * 256 + k0 + bkc];
    bvb = *(const float4*)&Ag[(size_t)(n0 + brow) * 256 + k0 + bkc + 4];
  };
  auto swrite = [&](int buf) {
    As[buf][akc + 0][arow] = av.x;
    As[buf][akc + 1][arow] = av.y;
    As[buf][akc + 2][arow] = av.z;
    As[buf][akc + 3][arow] = av.w;
    Bs[buf][bkc + 0][brow] = bva.x;
    Bs[buf][bkc + 1][brow] = bva.y;
    Bs[buf][bkc + 2][brow] = bva.z;
    Bs[buf][bkc + 3][brow] = bva.w;
    Bs[buf][bkc + 4][brow] = bvb.x;
    Bs[buf][bkc + 5][brow] = bvb.y;
    Bs[buf][bkc + 6][brow] = bvb.z;
    Bs[buf][bkc + 7][brow] = bvb.w;
  };
  gload(0);
  swrite(0);
  __syncthreads();
  for (int s = 0; s < 16; ++s) {
    if (s < 15) gload((s + 1) * 16);
    const int buf = s & 1;
#pragma unroll
    for (int kk = 0; kk < 16; ++kk) {
      const float4 a0 = *(const float4*)&As[buf][kk][ty * 4];
      const float4 b0 = *(const float4*)&Bs[buf][kk][tx * 4];
      const float4 b1 = *(const float4*)&Bs[buf][kk][64 + tx * 4];
      const float aa[4] = {a0.x, a0.y, a0.z, a0.w};
      const float bb[8] = {b0.x, b0.y, b0.z, b0.w, b1.x, b1.y, b1.z, b1.w};
#pragma unroll
      for (int i = 0; i < 4; ++i)
#pragma unroll
        for (int j = 0; j < 8; ++j) acc[i][j] = fmaf(aa[i], bb[j], acc[i][j]);
    }
    if (s < 15) swrite((s + 1) & 1);
    __syncthreads();
  }
  const int c0 = n0 + tx * 4, c1 = n0 + 64 + tx * 4;
#pragma unroll
  for (int i = 0; i < 4; ++i) {
    const int row = m0 + ty * 4 + i;
    float4 o0 = {acc[i][0], acc[i][1], acc[i][2], acc[i][3]};
    float4 o1 = {acc[i][4], acc[i][5], acc[i][6], acc[i][7]};
    *(float4*)&Cg[(size_t)row * 256 + c0] = o0;
    *(float4*)&Cg[(size_t)row * 256 + c1] = o1;
    if (row >= c0 && row < c0 + 4) sq[row] = acc[i][row - c0];
    if (row >= c1 && row < c1 + 4) sq[row] = acc[i][4 + row - c1];
  }
  if (bx == 1 && by < 2) {  // mirror into the skipped lower-left region
#pragma unroll
    for (int j = 0; j < 4; ++j) {
      const size_t col0 = (size_t)(n0 + tx * 4 + j);
      const size_t col1 = (size_t)(n0 + 64 + tx * 4 + j);
      float4 t0 = {acc[0][j], acc[1][j], acc[2][j], acc[3][j]};
      float4 t1 = {acc[0][4 + j], acc[1][4 + j], acc[2][4 + j], acc[3][4 + j]};
      *(float4*)&Cg[col0 * 256 + m0 + ty * 4] = t0;
      *(float4*)&Cg[col1 * 256 + m0 + ty * 4] = t1;
    }
  }
}

// -- MFMA GEMM merged: [2][16384,256] fp32 h @ w1cat^T -> baseb2, n1b2 (f16) ---
__global__ __launch_bounds__(256, 2) void mlp1m_mfma_k(const float* __restrict__ h2,
                                                       const f16* __restrict__ Bt,
                                                       const float* __restrict__ biascat,
                                                       f16* __restrict__ baseb2,
                                                       f16* __restrict__ n1b2) {
  __shared__ char As[64 * 512];
  const int tid = threadIdx.x;
  const int l = tid & 63, wv = tid >> 6;
  const int r = l & 15, gq = l >> 4;
  const int half = blockIdx.y >> 8;
  const int m0 = (blockIdx.y & 255) * 64, n0 = blockIdx.x * 128;
  const float* A = h2 + (size_t)half * NR * ND;
  f16x8 bfr[2][8];
  float bv[2];
#pragma unroll
  for (int nt = 0; nt < 2; ++nt) {
    const int col = n0 + wv * 32 + nt * 16 + r;
    const f16* wb = Bt + (size_t)col * 256 + gq * 8;
#pragma unroll
    for (int ks = 0; ks < 8; ++ks) bfr[nt][ks] = *(const f16x8*)(wb + ks * 32);
    bv[nt] = biascat[col];
  }
  const int row = tid >> 2, ch = tid & 3;
  const float* ag = A + (size_t)(m0 + row) * 256 + ch * 64;
  char* lb = As + row * 512;
#pragma unroll
  for (int j = 0; j < 8; ++j) {
    const float4 x0 = *(const float4*)(ag + j * 8);
    const float4 x1 = *(const float4*)(ag + j * 8 + 4);
    f16x8 w = {(f16)x0.x, (f16)x0.y, (f16)x0.z, (f16)x0.w,
               (f16)x1.x, (f16)x1.y, (f16)x1.z, (f16)x1.w};
    *(f16x8*)(lb + (((ch * 128 + j * 16)) ^ ((row & 7) << 4))) = w;
  }
  __syncthreads();
  f32x4 acc[4][2];
#pragma unroll
  for (int mt = 0; mt < 4; ++mt)
#pragma unroll
    for (int nt = 0; nt < 2; ++nt) acc[mt][nt] = (f32x4){0.f, 0.f, 0.f, 0.f};
#pragma unroll
  for (int ks = 0; ks < 8; ++ks) {
    f16x8 a[4];
#pragma unroll
    for (int mt = 0; mt < 4; ++mt)
      a[mt] = *(const f16x8*)(As + (mt * 16 + r) * 512 + ((gq * 16 + ks * 64) ^ ((r & 7) << 4)));
#pragma unroll
    for (int mt = 0; mt < 4; ++mt)
#pragma unroll
      for (int nt = 0; nt < 2; ++nt)
        acc[mt][nt] = __builtin_amdgcn_mfma_f32_16x16x32_f16(a[mt], bfr[nt][ks], acc[mt][nt], 0, 0, 0);
  }
  f16* dst = ((n0 < 256) ? baseb2 : n1b2) + (size_t)half * NR * ND;
  const int cb = (n0 < 256) ? n0 : n0 - 256;
#pragma unroll
  for (int mt = 0; mt < 4; ++mt)
#pragma unroll
    for (int nt = 0; nt < 2; ++nt) {
      const int col = cb + wv * 32 + nt * 16 + r;
#pragma unroll
      for (int reg = 0; reg < 4; ++reg) {
        const int rw = m0 + mt * 16 + gq * 4 + reg;
        dst[(size_t)rw * 256 + col] = (f16)(acc[mt][nt][reg] + bv[nt]);
      }
    }
}

// ---------------- MFMA cost GEMM -> P0 = exp(corr/(nA nB lam)), XCD-swizzled --
__global__ __launch_bounds__(256, 2) void cost_mfma_k(const f16* __restrict__ featT,
                                                      const f16* __restrict__ featD,
                                                      const float* __restrict__ nA,
                                                      const float* __restrict__ nB,
                                                      const float* __restrict__ eps,
                                                      float* __restrict__ P) {
  __shared__ char As[64 * 512];
  const int flat = ((blockIdx.x & 7) << 6) | (blockIdx.x >> 3);
  const int bx = flat & 1, by = (flat >> 1) & 3, g = flat >> 3;
  const f16* A = featT + (size_t)g * NM * ND;
  const f16* Bt = featD + (size_t)g * NM * ND;
  const int tid = threadIdx.x;
  const int l = tid & 63, wv = tid >> 6;
  const int r = l & 15, gq = l >> 4;
  const int m0 = by * 64, n0 = bx * 128;
  f16x8 bfr[2][8];
  float rnb[2];
#pragma unroll
  for (int nt = 0; nt < 2; ++nt) {
    const int col = n0 + wv * 32 + nt * 16 + r;
    const f16* wb = Bt + (size_t)col * 256 + gq * 8;
#pragma unroll
    for (int ks = 0; ks < 8; ++ks) bfr[nt][ks] = *(const f16x8*)(wb + ks * 32);
    rnb[nt] = 1.0f / nB[g * NM + col];
  }
  const int row = tid >> 2, ch = tid & 3;
  const char* ag = (const char*)(A + (size_t)(m0 + row) * 256) + ch * 128;
  char* lb = As + row * 512;
#pragma unroll
  for (int j = 0; j < 8; ++j)
    *(f16x8*)(lb + (((ch * 128 + j * 16)) ^ ((row & 7) << 4))) = *(const f16x8*)(ag + j * 16);
  __syncthreads();
  f32x4 acc[4][2];
#pragma unroll
  for (int mt = 0; mt < 4; ++mt)
#pragma unroll
    for (int nt = 0; nt < 2; ++nt) acc[mt][nt] = (f32x4){0.f, 0.f, 0.f, 0.f};
#pragma unroll
  for (int ks = 0; ks < 8; ++ks) {
    f16x8 a[4];
#pragma unroll
    for (int mt = 0; mt < 4; ++mt)
      a[mt] = *(const f16x8*)(As + (mt * 16 + r) * 512 + ((gq * 16 + ks * 64) ^ ((r & 7) << 4)));
#pragma unroll
    for (int mt = 0; mt < 4; ++mt)
#pragma unroll
      for (int nt = 0; nt < 2; ++nt)
        acc[mt][nt] = __builtin_amdgcn_mfma_f32_16x16x32_f16(a[mt], bfr[nt][ks], acc[mt][nt], 0, 0, 0);
  }
  const float inv_lam = 1.0f / (expf(eps[0]) + 0.03f);
#pragma unroll
  for (int mt = 0; mt < 4; ++mt) {
    float ria[4];
#pragma unroll
    for (int reg = 0; reg < 4; ++reg)
      ria[reg] = inv_lam / nA[g * NM + m0 + mt * 16 + gq * 4 + reg];
#pragma unroll
    for (int nt = 0; nt < 2; ++nt) {
      const int col = n0 + wv * 32 + nt * 16 + r;
#pragma unroll
      for (int reg = 0; reg < 4; ++reg) {
        const int rw = m0 + mt * 16 + gq * 4 + reg;
        P[(size_t)g * NM * NM + (size_t)rw * 256 + col] =
            expf(acc[mt][nt][reg] * ria[reg] * rnb[nt]);
      }
    }
  }
}

// ------- top-16 nearest neighbors, merged over both halves (wave/row) --------
__global__ __launch_bounds__(256) void topk2_k(const float* __restrict__ S0,
                                               const float* __restrict__ S1,
                                               const float* __restrict__ sq2,
                                               int* __restrict__ idx2) {
  const int w = threadIdx.x >> 6, lane = threadIdx.x & 63;
  const int row = blockIdx.x * 4 + w;  // 0..32767
  const int half = row >> 14;
  const int lrow = row & (NR - 1);
  const int g = lrow >> 8, m = lrow & 255;
  const float* Srow = (half ? S1 : S0) + (size_t)lrow * NM;
  const float* sqg = sq2 + half * NR + g * NM;
  int* idx = idx2 + (size_t)half * NR * NK;
  const float sm = sqg[m];
  const float4 sv = *(const float4*)&Srow[lane * 4];
  const float4 qv = *(const float4*)&sqg[lane * 4];
  float cand[4] = {sm + qv.x - 2.f * sv.x, sm + qv.y - 2.f * sv.y, sm + qv.z - 2.f * sv.z,
                   sm + qv.w - 2.f * sv.w};
#pragma unroll
  for (int t = 0; t < 4; ++t)
    if (lane * 4 + t == m) cand[t] = 1e30f;
  for (int rnd = 0; rnd < NK; ++rnd) {
    float bvv = cand[0];
    int bi = lane * 4;
#pragma unroll
    for (int t = 1; t < 4; ++t)
      if (cand[t] < bvv) {
        bvv = cand[t];
        bi = lane * 4 + t;
      }
#pragma unroll
    for (int off = 1; off < 64; off <<= 1) {
      const float ov = __shfl_xor(bvv, off);
      const int oi = __shfl_xor(bi, off);
      if (ov < bvv || (ov == bvv && oi < bi)) {
        bvv = ov;
        bi = oi;
      }
    }
    if (lane == 0) idx[(size_t)lrow * NK + rnd] = bi;
    if ((bi >> 2) == lane) cand[bi & 3] = 1e30f;
  }
}

// --------- edge MLP v10: v8 structure, merged over both graph-convs ----------
__global__ __launch_bounds__(512, 4) void edgemlp_mfma10_k(
    const f16* __restrict__ baseb2, const f16* __restrict__ n1b2, const int* __restrict__ idx2,
    const f16* __restrict__ w2t, const float* __restrict__ b2, f16* __restrict__ featf2,
    float* __restrict__ nrm2) {
  __shared__ unsigned E[2][2][512 * 4];  // [buf][node-in-pair][slot*4u] = 32 KB
  __shared__ int sidx[NB * NK];          // 512 ints
  __shared__ float normp[NB][8];
  const int tid = threadIdx.x;
  const int l = tid & 63, wv = tid >> 6;
  const size_t SZH = (size_t)NR * ND;
  const int bid = blockIdx.x;  // 0..1023
  const int half = bid >> 9;
  const int b9 = bid & 511;
  const int blk = ((b9 & 7) << 6) | (b9 >> 3);  // XCD: 8 graphs each
  const int node0 = blk * NB;
  const int g = node0 >> 8;
  const f16* baseb = baseb2 + (size_t)half * SZH;
  const f16* n1b = n1b2 + (size_t)half * SZH;
  const int* idx = idx2 + (size_t)half * NR * NK;
  f16* featf = featf2 + (size_t)half * SZH;
  float* nrm = nrm2 + (size_t)half * NR;
  const int r = l & 15, gq = l >> 4;
  sidx[tid] = idx[(size_t)node0 * NK + tid];
  f16x8 bfr[2][8];
  float b2v[2];
#pragma unroll
  for (int t = 0; t < 2; ++t) {
    const int nb = wv * 2 + t;
    const f16* wb = w2t + (size_t)(nb * 16 + r) * 256 + gq * 8;
#pragma unroll
    for (int ks = 0; ks < 8; ++ks) bfr[t][ks] = *(const f16x8*)(wb + ks * 32);
    b2v[t] = b2[nb * 16 + r];
  }
  __syncthreads();  // sidx visible
  const int r_s = tid & 15;
  const int col_s = ((tid >> 6) * 32) + (((tid >> 4) & 3) * 8);
  u32x4 bs0, ns0, bs1, ns1;
  auto sload = [&](int s) {
    const int na = s * 2;
    bs0 = *(const u32x4*)(baseb + (((size_t)(node0 + na)) << 8) + col_s);
    ns0 = *(const u32x4*)(n1b + ((((size_t)g << 8) + sidx[na * NK + r_s]) << 8) + col_s);
    bs1 = *(const u32x4*)(baseb + (((size_t)(node0 + na + 1)) << 8) + col_s);
    ns1 = *(const u32x4*)(n1b + ((((size_t)g << 8) + sidx[(na + 1) * NK + r_s]) << 8) + col_s);
  };
  auto swrite = [&](int s) {
    const int buf = s & 1;
    u32x4 w0, w1;
#pragma unroll
    for (int q = 0; q < 4; ++q) {
      w0[q] = pkrelu(bs0[q], ns0[q]);
      w1[q] = pkrelu(bs1[q], ns1[q]);
    }
    *(u32x4*)&E[buf][0][tid * 4] = w0;
    *(u32x4*)&E[buf][1][tid * 4] = w1;
  };
  sload(0);
  swrite(0);
  __syncthreads();
  for (int s = 0; s < NB / 2; ++s) {
    if (s + 1 < NB / 2) sload(s + 1);
    const int buf = s & 1;
#pragma unroll
    for (int q = 0; q < 2; ++q) {
      const char* eb = (const char*)&E[buf][q][0];
      f32x4 acc0 = (f32x4){0.f, 0.f, 0.f, 0.f};
      f32x4 acc1 = (f32x4){0.f, 0.f, 0.f, 0.f};
#pragma unroll
      for (int ks = 0; ks < 8; ++ks) {
        const f16x8 a = *(const f16x8*)(eb + ks * 1024 + l * 16);
        acc0 = __builtin_amdgcn_mfma_f32_16x16x32_f16(a, bfr[0][ks], acc0, 0, 0, 0);
        acc1 = __builtin_amdgcn_mfma_f32_16x16x32_f16(a, bfr[1][ks], acc1, 0, 0, 0);
      }
      const int nd = node0 + s * 2 + q;
      float m0v = fmaxf(fmaxf(acc0[0], acc0[1]), fmaxf(acc0[2], acc0[3]));
      m0v = fmaxf(m0v, __shfl_xor(m0v, 16));
      m0v = fmaxf(m0v, __shfl_xor(m0v, 32));
      float m1v = fmaxf(fmaxf(acc1[0], acc1[1]), fmaxf(acc1[2], acc1[3]));
      m1v = fmaxf(m1v, __shfl_xor(m1v, 16));
      m1v = fmaxf(m1v, __shfl_xor(m1v, 32));
      const f16 h0 = (f16)(m0v + b2v[0]);
      const f16 h1 = (f16)(m1v + b2v[1]);
      if (gq == 0) {
        featf[((size_t)nd << 8) + (wv * 2 + 0) * 16 + r] = h0;
        featf[((size_t)nd << 8) + (wv * 2 + 1) * 16 + r] = h1;
      }
      const float o0 = (float)h0, o1 = (float)h1;
      float ss = o0 * o0 + o1 * o1;
      ss += __shfl_xor(ss, 1);
      ss += __shfl_xor(ss, 2);
      ss += __shfl_xor(ss, 4);
      ss += __shfl_xor(ss, 8);
      if (l == 0) normp[s * 2 + q][wv] = ss;
    }
    if (s + 1 < NB / 2) swrite(s + 1);
    __syncthreads();
  }
  if (tid < NB) {
    float s = 0.f;
#pragma unroll
    for (int w = 0; w < 8; ++w) s += normp[tid][w];
    nrm[node0 + tid] = sqrtf(s);
  }
}

// ---------------- fused Sinkhorn, plain domain: block per graph, P in regs ----
__global__ __launch_bounds__(1024) void sinkhorn_k(float* __restrict__ P) {
  __shared__ float red[16][256];
  __shared__ float scal[256];
  const int t = threadIdx.x;
  const int tc = t & 15;
  const int trw = t >> 4;
  const int wv = t >> 6, l = t & 63;
  float* Pg = P + (size_t)blockIdx.x * NM * NM;
  float p[4][16];
#pragma unroll
  for (int i = 0; i < 4; ++i)
#pragma unroll
    for (int q = 0; q < 4; ++q)
      *(f32x4*)&p[i][q * 4] = *(const f32x4*)&Pg[(size_t)(trw * 4 + i) * NM + tc * 16 + q * 4];

  auto rowpass = [&]() {
#pragma unroll
    for (int i = 0; i < 4; ++i) {
      float s = p[i][0];
#pragma unroll
      for (int j = 1; j < 16; ++j) s += p[i][j];
      s += __shfl_xor(s, 1);
      s += __shfl_xor(s, 2);
      s += __shfl_xor(s, 4);
      s += __shfl_xor(s, 8);
      const float sc = MASSF / s;
#pragma unroll
      for (int j = 0; j < 16; ++j) p[i][j] *= sc;
    }
  };
  auto colpass = [&]() {
    float tmp[16];
#pragma unroll
    for (int j = 0; j < 16; ++j) tmp[j] = ((p[0][j] + p[1][j]) + (p[2][j] + p[3][j]));
#pragma unroll
    for (int j = 0; j < 16; ++j) {
      tmp[j] += __shfl_xor(tmp[j], 16);
      tmp[j] += __shfl_xor(tmp[j], 32);
    }
    if (l < 16) {
#pragma unroll
      for (int q = 0; q < 4; ++q)
        *(f32x4*)&red[wv][l * 16 + q * 4] = *(const f32x4*)&tmp[q * 4];
    }
    __syncthreads();
    if (t < 256) {
      float s = red[0][t];
#pragma unroll
      for (int w = 1; w < 16; ++w) s += red[w][t];
      scal[t] = MASSF / s;
    }
    __syncthreads();
#pragma unroll
    for (int j = 0; j < 16; ++j) {
      const float sc = scal[tc * 16 + j];
#pragma unroll
      for (int i = 0; i < 4; ++i) p[i][j] *= sc;
    }
    __syncthreads();
  };
  for (int it = 0; it < 7; ++it) {
    rowpass();
    colpass();
  }
  rowpass();
#pragma unroll
  for (int i = 0; i < 4; ++i)
#pragma unroll
    for (int q = 0; q < 4; ++q)
      *(f32x4*)&Pg[(size_t)(trw * 4 + i) * NM + tc * 16 + q * 4] = *(const f32x4*)&p[i][q * 4];
}

extern "C" void kernel_launch(void* const* d_in, const int* in_sizes, int n_in, void* d_out,
                              int out_size, void* d_ws, size_t ws_size, hipStream_t stream) {
  const float* tra_x = (const float*)d_in[0];
  const float* det_x = (const float*)d_in[1];
  const float* W_enc = (const float*)d_in[2];
  const float* b_enc = (const float*)d_in[3];
  const float* W1 = (const float*)d_in[4];
  const float* b1 = (const float*)d_in[5];
  const float* W2 = (const float*)d_in[6];
  const float* b2 = (const float*)d_in[7];
  const float* eps = (const float*)d_in[8];
  float* out = (float*)d_out;

  const size_t SZ = (size_t)NR * ND;
  float* h2 = (float*)d_ws;          // 2*SZ fp32
  f16* baseb = (f16*)(h2 + 2 * SZ);  // 2*SZ f16
  f16* n1b = baseb + 2 * SZ;         // 2*SZ f16
  f16* featT = n1b + 2 * SZ;         // SZ f16
  f16* featD = featT + SZ;           // SZ f16
  float* S1 = (float*)featT;         // SZ fp32 alias — dead until edgemlp
  float* sq2 = (float*)(featD + SZ); // 2*NR
  float* nT = sq2 + 2 * NR;          // NR ; nD contiguous
  float* nD = nT + NR;
  int* idx = (int*)(nD + NR);        // 2*NR*NK
  f16* w2t = (f16*)(idx + 2 * (size_t)NR * NK);
  f16* w1cat = w2t + 256 * 256;
  float* biascat = (float*)(w1cat + 512 * 256);
  float* S0 = out;  // gram scratch for half 0 lives in d_out until cost overwrites

  prep_k<<<768, 256, 0, stream>>>(W1, b1, W2, w2t, w1cat, biascat);
  gemm_nn2m_k<<<dim3(2, 512), 256, 0, stream>>>(tra_x, det_x, W_enc, b_enc, h2);
  mlp1m_mfma_k<<<dim3(4, 512), 256, 0, stream>>>(h2, w1cat, biascat, baseb, n1b);
  gemm_nt2m_k<<<1024, 256, 0, stream>>>(h2, S0, S1, sq2);
  topk2_k<<<8192, 256, 0, stream>>>(S0, S1, sq2, idx);
  edgemlp_mfma10_k<<<1024, 512, 0, stream>>>(baseb, n1b, idx, w2t, b2, featT, nT);
  cost_mfma_k<<<512, 256, 0, stream>>>(featT, featD, nT, nD, eps, out);
  sinkhorn_k<<<NG, 1024, 0, stream>>>(out);
}